// Round 1
// baseline (478.917 us; speedup 1.0000x reference)
//
#include <hip/hip_runtime.h>
#include <math.h>

#define S_LEN 2048
#define DM 1024
#define NH 16
#define HD 64
#define DFF 4096
#define MROWS 4096  // S_LEN * 2 batch

typedef unsigned short u16;
typedef __attribute__((ext_vector_type(8))) __bf16 bf16x8;
typedef __attribute__((ext_vector_type(4))) float f32x4;

__device__ __forceinline__ u16 f2bf(float f) {
  unsigned u = __float_as_uint(f);
  unsigned r = (u + 0x7fffu + ((u >> 16) & 1u)) >> 16;  // RNE
  return (u16)r;
}

__device__ __forceinline__ void gload_lds16(const void* g, void* l) {
  __builtin_amdgcn_global_load_lds((__attribute__((address_space(1))) void*)g,
                                   (__attribute__((address_space(3))) void*)l, 16, 0, 0);
}

// ---------- transpose + fp32->bf16 weights: W (K x N) -> Wt (N x K) ----------
__global__ __launch_bounds__(256) void k_transpose_bf16(const float* __restrict__ W,
                                                        u16* __restrict__ Wt, int K, int N) {
  __shared__ float tile[32][33];
  int n0 = blockIdx.x * 32, k0 = blockIdx.y * 32;
  int tx = threadIdx.x & 31, ty = threadIdx.x >> 5;
  #pragma unroll
  for (int r = ty; r < 32; r += 8) tile[r][tx] = W[(size_t)(k0 + r) * N + n0 + tx];
  __syncthreads();
  #pragma unroll
  for (int r = ty; r < 32; r += 8) Wt[(size_t)(n0 + r) * K + k0 + tx] = f2bf(tile[tx][r]);
}

// ---------- fp32 -> bf16 elementwise (vectorized) ----------
__global__ __launch_bounds__(256) void k_f2bf4(const float4* __restrict__ in,
                                               ushort4* __restrict__ out, int n4) {
  int i = blockIdx.x * 256 + threadIdx.x;
  if (i >= n4) return;
  float4 v = in[i];
  ushort4 o;
  o.x = f2bf(v.x); o.y = f2bf(v.y); o.z = f2bf(v.z); o.w = f2bf(v.w);
  out[i] = o;
}

// ---------- RoPE cos/sin table: [S_LEN][32] ----------
__global__ __launch_bounds__(256) void k_rope_table(float* __restrict__ cosT,
                                                    float* __restrict__ sinT) {
  int idx = blockIdx.x * 256 + threadIdx.x;
  if (idx >= S_LEN * 32) return;
  int s = idx >> 5, i = idx & 31;
  float inv = powf(10000.f, -(float)(2 * i) / 64.f);
  float ang = (float)s * inv;
  cosT[idx] = cosf(ang);
  sinT[idx] = sinf(ang);
}

// ---------- m97-structure bf16 GEMM: C = A(MxK) @ Bt(NxK)^T + bias [+epilogue] ----------
enum { EPI_F32 = 0, EPI_ADD_F32 = 1, EPI_RELU_BF16 = 2 };

template <int EPI>
__global__ __launch_bounds__(256) void k_gemm(const u16* __restrict__ A, const u16* __restrict__ Bt,
                                              const float* __restrict__ bias,
                                              const float* __restrict__ resid,
                                              float* __restrict__ Cf, u16* __restrict__ Cb,
                                              int M, int N, int K, int ldc) {
  __shared__ __attribute__((aligned(16))) u16 As[128 * 32];
  __shared__ __attribute__((aligned(16))) u16 Bs[128 * 32];
  int m0 = blockIdx.y * 128, n0 = blockIdx.x * 128;
  int tid = threadIdx.x;
  int lane = tid & 63, w = tid >> 6;
  int wm = (w >> 1) * 64, wn = (w & 1) * 64;
  int l15 = lane & 15, l4 = lane >> 4;

  f32x4 acc[4][4] = {};

  for (int k0 = 0; k0 < K; k0 += 32) {
    __syncthreads();  // prior iter's ds_reads done before overwrite
    #pragma unroll
    for (int i = 0; i < 2; ++i) {
      int sl = i * 256 + w * 64;  // wave-uniform LDS base slot
      int sg = sl + lane;         // per-lane global slot
      const u16* ga = A + (size_t)(m0 + (sg >> 2)) * K + k0 + (sg & 3) * 8;
      gload_lds16(ga, &As[sl * 8]);
      const u16* gb = Bt + (size_t)(n0 + (sg >> 2)) * K + k0 + (sg & 3) * 8;
      gload_lds16(gb, &Bs[sl * 8]);
    }
    __syncthreads();  // drains vmcnt -> tiles ready

    bf16x8 af[4], bfr[4];
    #pragma unroll
    for (int i = 0; i < 4; ++i)
      af[i] = *(const bf16x8*)&As[(wm + i * 16 + l15) * 32 + l4 * 8];
    #pragma unroll
    for (int j = 0; j < 4; ++j)
      bfr[j] = *(const bf16x8*)&Bs[(wn + j * 16 + l15) * 32 + l4 * 8];
    #pragma unroll
    for (int i = 0; i < 4; ++i)
      #pragma unroll
      for (int j = 0; j < 4; ++j)
        acc[i][j] = __builtin_amdgcn_mfma_f32_16x16x32_bf16(af[i], bfr[j], acc[i][j], 0, 0, 0);
  }

  #pragma unroll
  for (int i = 0; i < 4; ++i) {
    #pragma unroll
    for (int j = 0; j < 4; ++j) {
      int col = n0 + wn + j * 16 + l15;
      float bv = bias[col];
      #pragma unroll
      for (int r = 0; r < 4; ++r) {
        int m = m0 + wm + i * 16 + l4 * 4 + r;  // C/D: col=lane&15, row=(lane>>4)*4+reg
        float v = acc[i][j][r] + bv;
        size_t o = (size_t)m * ldc + col;
        if (EPI == EPI_F32) Cf[o] = v;
        else if (EPI == EPI_ADD_F32) Cf[o] = v + resid[o];
        else Cb[o] = f2bf(fmaxf(v, 0.f));
      }
    }
  }
}

// ---------- RoPE + head-split: QKV f32 (M x 3072) -> Qh,Kh (bh,s,d) bf16; Vt (bh,d,s) bf16 ----------
__global__ __launch_bounds__(256) void k_rope_heads(const float* __restrict__ QKV,
                                                    const float* __restrict__ cosT,
                                                    const float* __restrict__ sinT,
                                                    u16* __restrict__ Qh, u16* __restrict__ Kh,
                                                    u16* __restrict__ Vt) {
  int idx = blockIdx.x * 256 + threadIdx.x;
  if (idx >= MROWS * 512) return;
  int m = idx >> 9, c2 = idx & 511;
  int h = c2 >> 5, i = c2 & 31, d = 2 * i;
  int s = m >> 1, b = m & 1;
  int bh = b * NH + h;
  size_t base = (size_t)m * 3072 + h * 64 + d;
  float q0 = QKV[base], q1 = QKV[base + 1];
  float k0 = QKV[base + 1024], k1 = QKV[base + 1025];
  float v0 = QKV[base + 2048], v1 = QKV[base + 2049];
  float c = cosT[s * 32 + i], sn = sinT[s * 32 + i];
  size_t ho = ((size_t)bh * S_LEN + s) * 64 + d;
  Qh[ho]     = f2bf(q0 * c - q1 * sn);  // x'[2i]   = x[2i]*c - x[2i+1]*s
  Qh[ho + 1] = f2bf(q1 * c + q0 * sn);  // x'[2i+1] = x[2i+1]*c + x[2i]*s
  Kh[ho]     = f2bf(k0 * c - k1 * sn);
  Kh[ho + 1] = f2bf(k1 * c + k0 * sn);
  size_t vo = ((size_t)bh * 64 + d) * S_LEN + s;
  Vt[vo] = f2bf(v0);
  Vt[vo + S_LEN] = f2bf(v1);
}

// ---------- flash attention: per (bh, q-block of 64). 4 waves x 16 q-rows ----------
__global__ __launch_bounds__(256) void k_attn(const u16* __restrict__ Qh, const u16* __restrict__ Kh,
                                              const u16* __restrict__ Vt,
                                              const float* __restrict__ mask,
                                              u16* __restrict__ Out) {
  __shared__ __attribute__((aligned(16))) u16 Ks[64 * 64];       // [kpos][d]
  __shared__ __attribute__((aligned(16))) u16 Vs[64 * 64];       // [d][kpos]
  __shared__ __attribute__((aligned(16))) u16 Ps[4 * 16 * 64];   // per-wave [qrow][kpos]
  int bh = blockIdx.y;
  int q0 = blockIdx.x * 64;
  int b = bh >> 4, h = bh & 15;
  int tid = threadIdx.x, lane = tid & 63, w = tid >> 6;
  int l15 = lane & 15, l4 = lane >> 4;

  // Q fragments held in registers for the whole kernel (A-frag: row=lane&15, k=(lane>>4)*8..)
  int qrow = q0 + w * 16 + l15;
  const u16* qp = Qh + ((size_t)bh * S_LEN + qrow) * 64 + l4 * 8;
  bf16x8 qa0 = *(const bf16x8*)qp;
  bf16x8 qa1 = *(const bf16x8*)(qp + 32);

  float m_run[4], l_run[4];
  f32x4 o_acc[4] = {};
  #pragma unroll
  for (int r = 0; r < 4; ++r) { m_run[r] = -1e30f; l_run[r] = 0.f; }

  for (int kv0 = 0; kv0 < S_LEN; kv0 += 64) {
    __syncthreads();  // prior PV reads of Vs done before restage
    #pragma unroll
    for (int i = 0; i < 2; ++i) {
      int sl = i * 256 + w * 64;
      int sg = sl + lane;
      const u16* gk = Kh + ((size_t)bh * S_LEN + kv0 + (sg >> 3)) * 64 + (sg & 7) * 8;
      gload_lds16(gk, &Ks[sl * 8]);
      const u16* gv = Vt + ((size_t)bh * 64 + (sg >> 3)) * S_LEN + kv0 + (sg & 7) * 8;
      gload_lds16(gv, &Vs[sl * 8]);
    }
    __syncthreads();

    // S = Q @ K^T  (16 q-rows x 64 keys per wave)
    f32x4 sc[4] = {};
    #pragma unroll
    for (int ks = 0; ks < 2; ++ks) {
      bf16x8 qa = ks ? qa1 : qa0;
      #pragma unroll
      for (int j = 0; j < 4; ++j) {
        bf16x8 kb = *(const bf16x8*)&Ks[(j * 16 + l15) * 64 + ks * 32 + l4 * 8];
        sc[j] = __builtin_amdgcn_mfma_f32_16x16x32_bf16(qa, kb, sc[j], 0, 0, 0);
      }
    }

    // online softmax (rows: (lane>>4)*4+r; 16-lane-group shfl reduce)
    #pragma unroll
    for (int r = 0; r < 4; ++r) {
      int qg = q0 + w * 16 + l4 * 4 + r;
      float mx = -1e30f;
      #pragma unroll
      for (int j = 0; j < 4; ++j) {
        float v = sc[j][r] * 0.125f;  // 1/sqrt(64)
        if (mask[(size_t)qg * S_LEN + kv0 + j * 16 + l15] < 0.1f) v = -1e30f;
        sc[j][r] = v;
        mx = fmaxf(mx, v);
      }
      #pragma unroll
      for (int off = 8; off >= 1; off >>= 1) mx = fmaxf(mx, __shfl_xor(mx, off, 64));
      float mn = fmaxf(m_run[r], mx);
      float corr = __expf(m_run[r] - mn);
      float rs = 0.f;
      #pragma unroll
      for (int j = 0; j < 4; ++j) {
        float p = __expf(sc[j][r] - mn);
        sc[j][r] = p;
        rs += p;
      }
      #pragma unroll
      for (int off = 8; off >= 1; off >>= 1) rs += __shfl_xor(rs, off, 64);
      m_run[r] = mn;
      l_run[r] = l_run[r] * corr + rs;
      #pragma unroll
      for (int jd = 0; jd < 4; ++jd) o_acc[jd][r] *= corr;
    }

    // P (C-layout) -> LDS -> A-frag layout for PV
    #pragma unroll
    for (int j = 0; j < 4; ++j)
      #pragma unroll
      for (int r = 0; r < 4; ++r)
        Ps[w * 1024 + (l4 * 4 + r) * 64 + j * 16 + l15] = f2bf(sc[j][r]);
    __syncthreads();

    // O += P @ V
    #pragma unroll
    for (int ks = 0; ks < 2; ++ks) {
      bf16x8 pa = *(const bf16x8*)&Ps[w * 1024 + l15 * 64 + ks * 32 + l4 * 8];
      #pragma unroll
      for (int jd = 0; jd < 4; ++jd) {
        bf16x8 vb = *(const bf16x8*)&Vs[(jd * 16 + l15) * 64 + ks * 32 + l4 * 8];
        o_acc[jd] = __builtin_amdgcn_mfma_f32_16x16x32_bf16(pa, vb, o_acc[jd], 0, 0, 0);
      }
    }
  }

  // write attn output in (m, d_model) layout for the O-projection GEMM
  #pragma unroll
  for (int jd = 0; jd < 4; ++jd) {
    #pragma unroll
    for (int r = 0; r < 4; ++r) {
      int qg = q0 + w * 16 + l4 * 4 + r;
      int mrow = qg * 2 + b;
      float ov = o_acc[jd][r] / l_run[r];
      Out[(size_t)mrow * DM + h * 64 + jd * 16 + l15] = f2bf(ov);
    }
  }
}

// ---------- LayerNorm over rows of 1024; optional bf16 copy ----------
__device__ __forceinline__ float wave_sum(float v) {
  #pragma unroll
  for (int off = 32; off >= 1; off >>= 1) v += __shfl_xor(v, off, 64);
  return v;
}

template <int WB>
__global__ __launch_bounds__(256) void k_layernorm(const float* __restrict__ X,
                                                   const float* __restrict__ gw,
                                                   const float* __restrict__ bw,
                                                   float* __restrict__ Yf, u16* __restrict__ Yb) {
  int m = blockIdx.x;
  int tid = threadIdx.x, lane = tid & 63, w = tid >> 6;
  __shared__ float part[4];
  __shared__ float shv[2];
  float4 v = ((const float4*)(X + (size_t)m * DM))[tid];
  float s = wave_sum(v.x + v.y + v.z + v.w);
  if (lane == 0) part[w] = s;
  __syncthreads();
  if (tid == 0) shv[0] = (part[0] + part[1] + part[2] + part[3]) * (1.f / DM);
  __syncthreads();
  float mu = shv[0];
  float d0 = v.x - mu, d1 = v.y - mu, d2 = v.z - mu, d3 = v.w - mu;
  float q = wave_sum(d0 * d0 + d1 * d1 + d2 * d2 + d3 * d3);
  if (lane == 0) part[w] = q;
  __syncthreads();
  if (tid == 0) shv[1] = rsqrtf((part[0] + part[1] + part[2] + part[3]) * (1.f / DM) + 1e-5f);
  __syncthreads();
  float rstd = shv[1];
  float4 g4 = ((const float4*)gw)[tid];
  float4 b4 = ((const float4*)bw)[tid];
  float y0 = d0 * rstd * g4.x + b4.x;
  float y1 = d1 * rstd * g4.y + b4.y;
  float y2 = d2 * rstd * g4.z + b4.z;
  float y3 = d3 * rstd * g4.w + b4.w;
  ((float4*)(Yf + (size_t)m * DM))[tid] = make_float4(y0, y1, y2, y3);
  if (WB) {
    ushort4 o;
    o.x = f2bf(y0); o.y = f2bf(y1); o.z = f2bf(y2); o.w = f2bf(y3);
    ((ushort4*)(Yb + (size_t)m * DM))[tid] = o;
  }
}

extern "C" void kernel_launch(void* const* d_in, const int* in_sizes, int n_in,
                              void* d_out, int out_size, void* d_ws, size_t ws_size,
                              hipStream_t stream) {
  (void)in_sizes; (void)n_in; (void)out_size; (void)ws_size;
  const float* src  = (const float*)d_in[0];
  const float* mask = (const float*)d_in[1];
  const float* Wq = (const float*)d_in[2];  const float* bq  = (const float*)d_in[3];
  const float* Wk = (const float*)d_in[4];  const float* bk  = (const float*)d_in[5];
  const float* Wv = (const float*)d_in[6];  const float* bv  = (const float*)d_in[7];
  const float* Wo = (const float*)d_in[8];  const float* bo  = (const float*)d_in[9];
  const float* W1 = (const float*)d_in[10]; const float* b1  = (const float*)d_in[11];
  const float* W2 = (const float*)d_in[12]; const float* b2  = (const float*)d_in[13];
  const float* g1 = (const float*)d_in[14]; const float* be1 = (const float*)d_in[15];
  const float* g2 = (const float*)d_in[16]; const float* be2 = (const float*)d_in[17];
  float* out = (float*)d_out;

  char* base = (char*)d_ws;
  size_t off = 0;
  auto carve = [&](size_t bytes) -> void* {
    void* r = base + off;
    off += (bytes + 255) & ~(size_t)255;
    return r;
  };
  u16* Wq_t = (u16*)carve(2ull * 1024 * 1024);
  u16* Wk_t = (u16*)carve(2ull * 1024 * 1024);
  u16* Wv_t = (u16*)carve(2ull * 1024 * 1024);
  u16* Wo_t = (u16*)carve(2ull * 1024 * 1024);
  u16* W1_t = (u16*)carve(2ull * 4096 * 1024);
  u16* W2_t = (u16*)carve(2ull * 1024 * 4096);
  u16* Xbf  = (u16*)carve(2ull * 4096 * 1024);
  float* cosT = (float*)carve(4ull * 2048 * 32);
  float* sinT = (float*)carve(4ull * 2048 * 32);
  u16* attn_out = (u16*)carve(2ull * 4096 * 1024);
  float* resid1 = (float*)carve(4ull * 4096 * 1024);
  float* QKV = (float*)carve(4ull * 4096 * 3072);       // 48MB; reused after rope_heads
  u16* Qh = (u16*)carve(2ull * 32 * 2048 * 64);
  u16* Kh = (u16*)carve(2ull * 32 * 2048 * 64);
  u16* Vt = (u16*)carve(2ull * 32 * 2048 * 64);
  // aliases (lifetimes verified: QKV dead after rope_heads; Qh/Kh/Vt dead after attn)
  u16* ff1 = (u16*)QKV;                                  // 32MB
  float* resid2 = (float*)((char*)QKV + 2ull * 4096 * 4096);  // +32MB, 16MB
  float* src2f = (float*)Qh;                             // 16MB (Qh+Kh)
  u16* src2b = (u16*)Vt;                                 // 8MB

  dim3 blk(256);
  // weight transpose+convert
  k_transpose_bf16<<<dim3(32, 32), blk, 0, stream>>>(Wq, Wq_t, 1024, 1024);
  k_transpose_bf16<<<dim3(32, 32), blk, 0, stream>>>(Wk, Wk_t, 1024, 1024);
  k_transpose_bf16<<<dim3(32, 32), blk, 0, stream>>>(Wv, Wv_t, 1024, 1024);
  k_transpose_bf16<<<dim3(32, 32), blk, 0, stream>>>(Wo, Wo_t, 1024, 1024);
  k_transpose_bf16<<<dim3(128, 32), blk, 0, stream>>>(W1, W1_t, 1024, 4096);
  k_transpose_bf16<<<dim3(32, 128), blk, 0, stream>>>(W2, W2_t, 4096, 1024);
  // src -> bf16
  k_f2bf4<<<dim3(4096), blk, 0, stream>>>((const float4*)src, (ushort4*)Xbf, 4096 * 1024 / 4);
  // rope table
  k_rope_table<<<dim3(256), blk, 0, stream>>>(cosT, sinT);
  // QKV projections (fp32 out, bias)
  k_gemm<EPI_F32><<<dim3(8, 32), blk, 0, stream>>>(Xbf, Wq_t, bq, nullptr, QKV + 0,    nullptr, 4096, 1024, 1024, 3072);
  k_gemm<EPI_F32><<<dim3(8, 32), blk, 0, stream>>>(Xbf, Wk_t, bk, nullptr, QKV + 1024, nullptr, 4096, 1024, 1024, 3072);
  k_gemm<EPI_F32><<<dim3(8, 32), blk, 0, stream>>>(Xbf, Wv_t, bv, nullptr, QKV + 2048, nullptr, 4096, 1024, 1024, 3072);
  // RoPE + head layout (+ V transpose)
  k_rope_heads<<<dim3(MROWS * 512 / 256), blk, 0, stream>>>(QKV, cosT, sinT, Qh, Kh, Vt);
  // attention
  k_attn<<<dim3(32, 32), blk, 0, stream>>>(Qh, Kh, Vt, mask, attn_out);
  // O projection + residual add (src)
  k_gemm<EPI_ADD_F32><<<dim3(8, 32), blk, 0, stream>>>(attn_out, Wo_t, bo, src, resid1, nullptr, 4096, 1024, 1024, 1024);
  // LN1 -> src2 (fp32 + bf16)
  k_layernorm<1><<<dim3(4096), blk, 0, stream>>>(resid1, g1, be1, src2f, src2b);
  // FF1 with ReLU (bf16 out)
  k_gemm<EPI_RELU_BF16><<<dim3(32, 32), blk, 0, stream>>>(src2b, W1_t, b1, nullptr, nullptr, ff1, 4096, 4096, 1024, 4096);
  // FF2 + residual add (src2)
  k_gemm<EPI_ADD_F32><<<dim3(8, 32), blk, 0, stream>>>(ff1, W2_t, b2, src2f, resid2, nullptr, 4096, 1024, 4096, 1024);
  // LN2 -> output
  k_layernorm<0><<<dim3(4096), blk, 0, stream>>>(resid2, g2, be2, out, nullptr);
}

// Round 2
// 441.171 us; speedup vs baseline: 1.0856x; 1.0856x over previous
//
#include <hip/hip_runtime.h>
#include <math.h>

#define S_LEN 2048
#define DM 1024
#define NH 16
#define HD 64
#define DFF 4096
#define MROWS 4096  // S_LEN * 2 batch
#define KVB 128

typedef unsigned short u16;
typedef __attribute__((ext_vector_type(8))) __bf16 bf16x8;
typedef __attribute__((ext_vector_type(4))) float f32x4;

__device__ __forceinline__ u16 f2bf(float f) {
  unsigned u = __float_as_uint(f);
  unsigned r = (u + 0x7fffu + ((u >> 16) & 1u)) >> 16;  // RNE
  return (u16)r;
}

__device__ __forceinline__ void gload_lds16(const void* g, void* l) {
  __builtin_amdgcn_global_load_lds((__attribute__((address_space(1))) void*)g,
                                   (__attribute__((address_space(3))) void*)l, 16, 0, 0);
}

// ---------- transpose + fp32->bf16 weights: W (K x N) -> Wt (N x K) ----------
__global__ __launch_bounds__(256) void k_transpose_bf16(const float* __restrict__ W,
                                                        u16* __restrict__ Wt, int K, int N) {
  __shared__ float tile[32][33];
  int n0 = blockIdx.x * 32, k0 = blockIdx.y * 32;
  int tx = threadIdx.x & 31, ty = threadIdx.x >> 5;
  #pragma unroll
  for (int r = ty; r < 32; r += 8) tile[r][tx] = W[(size_t)(k0 + r) * N + n0 + tx];
  __syncthreads();
  #pragma unroll
  for (int r = ty; r < 32; r += 8) Wt[(size_t)(n0 + r) * K + k0 + tx] = f2bf(tile[tx][r]);
}

// ---------- fp32 -> bf16 elementwise (vectorized) ----------
__global__ __launch_bounds__(256) void k_f2bf4(const float4* __restrict__ in,
                                               ushort4* __restrict__ out, int n4) {
  int i = blockIdx.x * 256 + threadIdx.x;
  if (i >= n4) return;
  float4 v = in[i];
  ushort4 o;
  o.x = f2bf(v.x); o.y = f2bf(v.y); o.z = f2bf(v.z); o.w = f2bf(v.w);
  out[i] = o;
}

// ---------- RoPE cos/sin table: [S_LEN][32] ----------
__global__ __launch_bounds__(256) void k_rope_table(float* __restrict__ cosT,
                                                    float* __restrict__ sinT) {
  int idx = blockIdx.x * 256 + threadIdx.x;
  if (idx >= S_LEN * 32) return;
  int s = idx >> 5, i = idx & 31;
  float inv = powf(10000.f, -(float)(2 * i) / 64.f);
  float ang = (float)s * inv;
  cosT[idx] = cosf(ang);
  sinT[idx] = sinf(ang);
}

// ---------- mask tile flags: 0 = all pass (>=0.1), 1 = mixed/masked ----------
__global__ __launch_bounds__(256) void k_mask_flags(const float* __restrict__ mask,
                                                    unsigned char* __restrict__ flags) {
  int kt = blockIdx.x, qt = blockIdx.y;
  const float* mp = mask + (size_t)(qt * 64) * S_LEN + kt * 64;
  int tr = threadIdx.x >> 2;
  int tc = (threadIdx.x & 3) * 16;
  int ok = 1;
  #pragma unroll
  for (int c = 0; c < 16; c += 4) {
    float4 v = *(const float4*)(mp + (size_t)tr * S_LEN + tc + c);
    ok &= (v.x >= 0.1f) & (v.y >= 0.1f) & (v.z >= 0.1f) & (v.w >= 0.1f);
  }
  ok = __all(ok) ? 1 : 0;
  __shared__ int sh[4];
  if ((threadIdx.x & 63) == 0) sh[threadIdx.x >> 6] = ok;
  __syncthreads();
  if (threadIdx.x == 0) flags[qt * 32 + kt] = (sh[0] & sh[1] & sh[2] & sh[3]) ? 0 : 1;
}

// ---------- m97-structure bf16 GEMM: C = A(MxK) @ Bt(NxK)^T + bias [+epilogue] ----------
enum { EPI_F32 = 0, EPI_ADD_F32 = 1, EPI_RELU_BF16 = 2 };

template <int EPI>
__global__ __launch_bounds__(256) void k_gemm(const u16* __restrict__ A, const u16* __restrict__ Bt,
                                              const float* __restrict__ bias,
                                              const float* __restrict__ resid,
                                              float* __restrict__ Cf, u16* __restrict__ Cb,
                                              int M, int N, int K, int ldc) {
  __shared__ __attribute__((aligned(16))) u16 As[128 * 32];
  __shared__ __attribute__((aligned(16))) u16 Bs[128 * 32];
  int m0 = blockIdx.y * 128, n0 = blockIdx.x * 128;
  int tid = threadIdx.x;
  int lane = tid & 63, w = tid >> 6;
  int wm = (w >> 1) * 64, wn = (w & 1) * 64;
  int l15 = lane & 15, l4 = lane >> 4;

  f32x4 acc[4][4] = {};

  for (int k0 = 0; k0 < K; k0 += 32) {
    __syncthreads();
    #pragma unroll
    for (int i = 0; i < 2; ++i) {
      int sl = i * 256 + w * 64;
      int sg = sl + lane;
      const u16* ga = A + (size_t)(m0 + (sg >> 2)) * K + k0 + (sg & 3) * 8;
      gload_lds16(ga, &As[sl * 8]);
      const u16* gb = Bt + (size_t)(n0 + (sg >> 2)) * K + k0 + (sg & 3) * 8;
      gload_lds16(gb, &Bs[sl * 8]);
    }
    __syncthreads();

    bf16x8 af[4], bfr[4];
    #pragma unroll
    for (int i = 0; i < 4; ++i)
      af[i] = *(const bf16x8*)&As[(wm + i * 16 + l15) * 32 + l4 * 8];
    #pragma unroll
    for (int j = 0; j < 4; ++j)
      bfr[j] = *(const bf16x8*)&Bs[(wn + j * 16 + l15) * 32 + l4 * 8];
    #pragma unroll
    for (int i = 0; i < 4; ++i)
      #pragma unroll
      for (int j = 0; j < 4; ++j)
        acc[i][j] = __builtin_amdgcn_mfma_f32_16x16x32_bf16(af[i], bfr[j], acc[i][j], 0, 0, 0);
  }

  #pragma unroll
  for (int i = 0; i < 4; ++i) {
    #pragma unroll
    for (int j = 0; j < 4; ++j) {
      int col = n0 + wn + j * 16 + l15;
      float bv = bias[col];
      #pragma unroll
      for (int r = 0; r < 4; ++r) {
        int m = m0 + wm + i * 16 + l4 * 4 + r;
        float v = acc[i][j][r] + bv;
        size_t o = (size_t)m * ldc + col;
        if (EPI == EPI_F32) Cf[o] = v;
        else if (EPI == EPI_ADD_F32) Cf[o] = v + resid[o];
        else Cb[o] = f2bf(fmaxf(v, 0.f));
      }
    }
  }
}

// ---------- RoPE + head-split; Q pre-scaled by 1/sqrt(HD) (exact pow2) ----------
__global__ __launch_bounds__(256) void k_rope_heads(const float* __restrict__ QKV,
                                                    const float* __restrict__ cosT,
                                                    const float* __restrict__ sinT,
                                                    u16* __restrict__ Qh, u16* __restrict__ Kh,
                                                    u16* __restrict__ Vt) {
  int idx = blockIdx.x * 256 + threadIdx.x;
  if (idx >= MROWS * 512) return;
  int m = idx >> 9, c2 = idx & 511;
  int h = c2 >> 5, i = c2 & 31, d = 2 * i;
  int s = m >> 1, b = m & 1;
  int bh = b * NH + h;
  size_t base = (size_t)m * 3072 + h * 64 + d;
  float q0 = QKV[base], q1 = QKV[base + 1];
  float k0 = QKV[base + 1024], k1 = QKV[base + 1025];
  float v0 = QKV[base + 2048], v1 = QKV[base + 2049];
  float c = cosT[s * 32 + i], sn = sinT[s * 32 + i];
  size_t ho = ((size_t)bh * S_LEN + s) * 64 + d;
  Qh[ho]     = f2bf((q0 * c - q1 * sn) * 0.125f);
  Qh[ho + 1] = f2bf((q1 * c + q0 * sn) * 0.125f);
  Kh[ho]     = f2bf(k0 * c - k1 * sn);
  Kh[ho + 1] = f2bf(k1 * c + k0 * sn);
  size_t vo = ((size_t)bh * 64 + d) * S_LEN + s;
  Vt[vo] = f2bf(v0);
  Vt[vo + S_LEN] = f2bf(v1);
}

// ---------- flash attention: KVB=128, XOR-swizzled LDS, mask tile-flags ----------
// Ks [128 key][64 d]   u16, row = 8 slots of 16B,  read slot ^= (row&7)
// Vs [64 d][128 key]   u16, row = 16 slots of 16B, read slot ^= (row&15)
// Ps per-wave [16 q][128 key] u16, 16 slots/row,   slot ^= row
__global__ __launch_bounds__(256) void k_attn(const u16* __restrict__ Qh, const u16* __restrict__ Kh,
                                              const u16* __restrict__ Vt,
                                              const float* __restrict__ mask,
                                              const unsigned char* __restrict__ flags,
                                              u16* __restrict__ Out) {
  __shared__ __attribute__((aligned(16))) u16 Ks[KVB * 64];
  __shared__ __attribute__((aligned(16))) u16 Vs[64 * KVB];
  __shared__ __attribute__((aligned(16))) u16 Ps[4 * 16 * KVB];
  int bh = blockIdx.y;
  int q0 = blockIdx.x * 64;
  int b = bh >> 4, h = bh & 15;
  int tid = threadIdx.x, lane = tid & 63, w = tid >> 6;
  int l15 = lane & 15, l4 = lane >> 4;
  int qt = q0 >> 6;

  int qrow = q0 + w * 16 + l15;
  const u16* qp = Qh + ((size_t)bh * S_LEN + qrow) * 64 + l4 * 8;
  bf16x8 qa0 = *(const bf16x8*)qp;
  bf16x8 qa1 = *(const bf16x8*)(qp + 32);

  float m_run[4], l_run[4];
  f32x4 o_acc[4] = {};
  #pragma unroll
  for (int r = 0; r < 4; ++r) { m_run[r] = -1e30f; l_run[r] = 0.f; }

  for (int kv0 = 0; kv0 < S_LEN; kv0 += KVB) {
    __syncthreads();  // prior iter's PV reads of Vs done before restage
    #pragma unroll
    for (int i = 0; i < 4; ++i) {
      int sl = i * 256 + w * 64;
      int sg = sl + lane;
      int kr = sg >> 3, kslot = sg & 7;
      const u16* gk = Kh + ((size_t)bh * S_LEN + kv0 + kr) * 64 + (kslot ^ (kr & 7)) * 8;
      gload_lds16(gk, &Ks[sl * 8]);
      int vr = sg >> 4, vslot = sg & 15;
      const u16* gv = Vt + ((size_t)bh * 64 + vr) * S_LEN + kv0 + ((vslot ^ (vr & 15))) * 8;
      gload_lds16(gv, &Vs[sl * 8]);
    }
    __syncthreads();  // drains vmcnt -> tiles ready

    // S = Q @ K^T  (16 q-rows x 128 keys per wave)
    f32x4 sc[8] = {};
    #pragma unroll
    for (int ks = 0; ks < 2; ++ks) {
      bf16x8 qa = ks ? qa1 : qa0;
      #pragma unroll
      for (int j = 0; j < 8; ++j) {
        int row = j * 16 + l15;
        bf16x8 kb = *(const bf16x8*)&Ks[row * 64 + ((ks * 4 + l4) ^ (row & 7)) * 8];
        sc[j] = __builtin_amdgcn_mfma_f32_16x16x32_bf16(qa, kb, sc[j], 0, 0, 0);
      }
    }

    int kt2 = kv0 >> 6;
    int fl = flags[qt * 32 + kt2] | flags[qt * 32 + kt2 + 1];

    // online softmax (row of quadrant = l4*4+r; reduce across 16-lane l15 group)
    #pragma unroll
    for (int r = 0; r < 4; ++r) {
      if (fl) {  // slow path: per-element mask (wave-uniform branch; off for all-pass)
        int qg = q0 + w * 16 + l4 * 4 + r;
        #pragma unroll
        for (int j = 0; j < 8; ++j)
          if (mask[(size_t)qg * S_LEN + kv0 + j * 16 + l15] < 0.1f) sc[j][r] = -1e30f;
      }
      float mx = m_run[r];
      #pragma unroll
      for (int j = 0; j < 8; ++j) mx = fmaxf(mx, sc[j][r]);
      #pragma unroll
      for (int off = 8; off >= 1; off >>= 1) mx = fmaxf(mx, __shfl_xor(mx, off, 64));
      float corr = __expf(m_run[r] - mx);
      float rs = 0.f;
      #pragma unroll
      for (int j = 0; j < 8; ++j) {
        float p = __expf(sc[j][r] - mx);
        sc[j][r] = p;
        rs += p;
      }
      #pragma unroll
      for (int off = 8; off >= 1; off >>= 1) rs += __shfl_xor(rs, off, 64);
      m_run[r] = mx;
      l_run[r] = l_run[r] * corr + rs;
      #pragma unroll
      for (int jd = 0; jd < 4; ++jd) o_acc[jd][r] *= corr;
    }

    // P (C-layout) -> LDS (swizzled) -> A-frag layout for PV
    #pragma unroll
    for (int j = 0; j < 8; ++j) {
      #pragma unroll
      for (int r = 0; r < 4; ++r) {
        int row = l4 * 4 + r;
        int col = j * 16 + l15;
        int slot = col >> 3;
        Ps[w * 2048 + row * 128 + (slot ^ row) * 8 + (col & 7)] = f2bf(sc[j][r]);
      }
    }
    __syncthreads();

    // O += P @ V
    #pragma unroll
    for (int ks2 = 0; ks2 < 4; ++ks2) {
      bf16x8 pa = *(const bf16x8*)&Ps[w * 2048 + l15 * 128 + ((ks2 * 4 + l4) ^ l15) * 8];
      #pragma unroll
      for (int jd = 0; jd < 4; ++jd) {
        int vrow = jd * 16 + l15;
        bf16x8 vb = *(const bf16x8*)&Vs[vrow * 128 + ((ks2 * 4 + l4) ^ (vrow & 15)) * 8];
        o_acc[jd] = __builtin_amdgcn_mfma_f32_16x16x32_bf16(pa, vb, o_acc[jd], 0, 0, 0);
      }
    }
  }

  // write attn output in (m, d_model) layout for the O-projection GEMM
  #pragma unroll
  for (int jd = 0; jd < 4; ++jd) {
    #pragma unroll
    for (int r = 0; r < 4; ++r) {
      int qg = q0 + w * 16 + l4 * 4 + r;
      int mrow = qg * 2 + b;
      float ov = o_acc[jd][r] / l_run[r];
      Out[(size_t)mrow * DM + h * 64 + jd * 16 + l15] = f2bf(ov);
    }
  }
}

// ---------- LayerNorm over rows of 1024; optional bf16 copy ----------
__device__ __forceinline__ float wave_sum(float v) {
  #pragma unroll
  for (int off = 32; off >= 1; off >>= 1) v += __shfl_xor(v, off, 64);
  return v;
}

template <int WB>
__global__ __launch_bounds__(256) void k_layernorm(const float* __restrict__ X,
                                                   const float* __restrict__ gw,
                                                   const float* __restrict__ bw,
                                                   float* __restrict__ Yf, u16* __restrict__ Yb) {
  int m = blockIdx.x;
  int tid = threadIdx.x, lane = tid & 63, w = tid >> 6;
  __shared__ float part[4];
  __shared__ float shv[2];
  float4 v = ((const float4*)(X + (size_t)m * DM))[tid];
  float s = wave_sum(v.x + v.y + v.z + v.w);
  if (lane == 0) part[w] = s;
  __syncthreads();
  if (tid == 0) shv[0] = (part[0] + part[1] + part[2] + part[3]) * (1.f / DM);
  __syncthreads();
  float mu = shv[0];
  float d0 = v.x - mu, d1 = v.y - mu, d2 = v.z - mu, d3 = v.w - mu;
  float q = wave_sum(d0 * d0 + d1 * d1 + d2 * d2 + d3 * d3);
  if (lane == 0) part[w] = q;
  __syncthreads();
  if (tid == 0) shv[1] = rsqrtf((part[0] + part[1] + part[2] + part[3]) * (1.f / DM) + 1e-5f);
  __syncthreads();
  float rstd = shv[1];
  float4 g4 = ((const float4*)gw)[tid];
  float4 b4 = ((const float4*)bw)[tid];
  float y0 = d0 * rstd * g4.x + b4.x;
  float y1 = d1 * rstd * g4.y + b4.y;
  float y2 = d2 * rstd * g4.z + b4.z;
  float y3 = d3 * rstd * g4.w + b4.w;
  ((float4*)(Yf + (size_t)m * DM))[tid] = make_float4(y0, y1, y2, y3);
  if (WB) {
    ushort4 o;
    o.x = f2bf(y0); o.y = f2bf(y1); o.z = f2bf(y2); o.w = f2bf(y3);
    ((ushort4*)(Yb + (size_t)m * DM))[tid] = o;
  }
}

extern "C" void kernel_launch(void* const* d_in, const int* in_sizes, int n_in,
                              void* d_out, int out_size, void* d_ws, size_t ws_size,
                              hipStream_t stream) {
  (void)in_sizes; (void)n_in; (void)out_size; (void)ws_size;
  const float* src  = (const float*)d_in[0];
  const float* mask = (const float*)d_in[1];
  const float* Wq = (const float*)d_in[2];  const float* bq  = (const float*)d_in[3];
  const float* Wk = (const float*)d_in[4];  const float* bk  = (const float*)d_in[5];
  const float* Wv = (const float*)d_in[6];  const float* bv  = (const float*)d_in[7];
  const float* Wo = (const float*)d_in[8];  const float* bo  = (const float*)d_in[9];
  const float* W1 = (const float*)d_in[10]; const float* b1  = (const float*)d_in[11];
  const float* W2 = (const float*)d_in[12]; const float* b2  = (const float*)d_in[13];
  const float* g1 = (const float*)d_in[14]; const float* be1 = (const float*)d_in[15];
  const float* g2 = (const float*)d_in[16]; const float* be2 = (const float*)d_in[17];
  float* out = (float*)d_out;

  char* base = (char*)d_ws;
  size_t off = 0;
  auto carve = [&](size_t bytes) -> void* {
    void* r = base + off;
    off += (bytes + 255) & ~(size_t)255;
    return r;
  };
  u16* Wq_t = (u16*)carve(2ull * 1024 * 1024);
  u16* Wk_t = (u16*)carve(2ull * 1024 * 1024);
  u16* Wv_t = (u16*)carve(2ull * 1024 * 1024);
  u16* Wo_t = (u16*)carve(2ull * 1024 * 1024);
  u16* W1_t = (u16*)carve(2ull * 4096 * 1024);
  u16* W2_t = (u16*)carve(2ull * 1024 * 4096);
  u16* Xbf  = (u16*)carve(2ull * 4096 * 1024);
  float* cosT = (float*)carve(4ull * 2048 * 32);
  float* sinT = (float*)carve(4ull * 2048 * 32);
  unsigned char* mflags = (unsigned char*)carve(1024);
  u16* attn_out = (u16*)carve(2ull * 4096 * 1024);
  float* resid1 = (float*)carve(4ull * 4096 * 1024);
  float* QKV = (float*)carve(4ull * 4096 * 3072);       // 48MB; reused after rope_heads
  u16* Qh = (u16*)carve(2ull * 32 * 2048 * 64);
  u16* Kh = (u16*)carve(2ull * 32 * 2048 * 64);
  u16* Vt = (u16*)carve(2ull * 32 * 2048 * 64);
  // aliases (lifetimes: QKV dead after rope_heads; Qh/Kh/Vt dead after attn)
  u16* ff1 = (u16*)QKV;                                  // 32MB
  float* resid2 = (float*)((char*)QKV + 2ull * 4096 * 4096);  // +32MB, 16MB
  float* src2f = (float*)Qh;                             // 16MB (Qh+Kh)
  u16* src2b = (u16*)Vt;                                 // 8MB

  dim3 blk(256);
  k_transpose_bf16<<<dim3(32, 32), blk, 0, stream>>>(Wq, Wq_t, 1024, 1024);
  k_transpose_bf16<<<dim3(32, 32), blk, 0, stream>>>(Wk, Wk_t, 1024, 1024);
  k_transpose_bf16<<<dim3(32, 32), blk, 0, stream>>>(Wv, Wv_t, 1024, 1024);
  k_transpose_bf16<<<dim3(32, 32), blk, 0, stream>>>(Wo, Wo_t, 1024, 1024);
  k_transpose_bf16<<<dim3(128, 32), blk, 0, stream>>>(W1, W1_t, 1024, 4096);
  k_transpose_bf16<<<dim3(32, 128), blk, 0, stream>>>(W2, W2_t, 4096, 1024);
  k_f2bf4<<<dim3(4096), blk, 0, stream>>>((const float4*)src, (ushort4*)Xbf, 4096 * 1024 / 4);
  k_rope_table<<<dim3(256), blk, 0, stream>>>(cosT, sinT);
  k_mask_flags<<<dim3(32, 32), blk, 0, stream>>>(mask, mflags);
  // QKV projections (fp32 out, bias)
  k_gemm<EPI_F32><<<dim3(8, 32), blk, 0, stream>>>(Xbf, Wq_t, bq, nullptr, QKV + 0,    nullptr, 4096, 1024, 1024, 3072);
  k_gemm<EPI_F32><<<dim3(8, 32), blk, 0, stream>>>(Xbf, Wk_t, bk, nullptr, QKV + 1024, nullptr, 4096, 1024, 1024, 3072);
  k_gemm<EPI_F32><<<dim3(8, 32), blk, 0, stream>>>(Xbf, Wv_t, bv, nullptr, QKV + 2048, nullptr, 4096, 1024, 1024, 3072);
  k_rope_heads<<<dim3(MROWS * 512 / 256), blk, 0, stream>>>(QKV, cosT, sinT, Qh, Kh, Vt);
  k_attn<<<dim3(32, 32), blk, 0, stream>>>(Qh, Kh, Vt, mask, mflags, attn_out);
  k_gemm<EPI_ADD_F32><<<dim3(8, 32), blk, 0, stream>>>(attn_out, Wo_t, bo, src, resid1, nullptr, 4096, 1024, 1024, 1024);
  k_layernorm<1><<<dim3(4096), blk, 0, stream>>>(resid1, g1, be1, src2f, src2b);
  k_gemm<EPI_RELU_BF16><<<dim3(32, 32), blk, 0, stream>>>(src2b, W1_t, b1, nullptr, nullptr, ff1, 4096, 4096, 1024, 4096);
  k_gemm<EPI_ADD_F32><<<dim3(8, 32), blk, 0, stream>>>(ff1, W2_t, b2, src2f, resid2, nullptr, 4096, 1024, 4096, 1024);
  k_layernorm<0><<<dim3(4096), blk, 0, stream>>>(resid2, g2, be2, out, nullptr);
}

// Round 3
// 441.093 us; speedup vs baseline: 1.0858x; 1.0002x over previous
//
#include <hip/hip_runtime.h>
#include <math.h>

#define S_LEN 2048
#define DM 1024
#define NH 16
#define HD 64
#define DFF 4096
#define MROWS 4096  // S_LEN * 2 batch
#define KVB 128

typedef unsigned short u16;
typedef __attribute__((ext_vector_type(8))) __bf16 bf16x8;
typedef __attribute__((ext_vector_type(4))) float f32x4;

__device__ __forceinline__ u16 f2bf(float f) {
  unsigned u = __float_as_uint(f);
  unsigned r = (u + 0x7fffu + ((u >> 16) & 1u)) >> 16;  // RNE
  return (u16)r;
}

__device__ __forceinline__ void gload_lds16(const void* g, void* l) {
  __builtin_amdgcn_global_load_lds((__attribute__((address_space(1))) void*)g,
                                   (__attribute__((address_space(3))) void*)l, 16, 0, 0);
}

// ---------- transpose + fp32->bf16 weights: W (K x N) -> Wt (N x K) ----------
__global__ __launch_bounds__(256) void k_transpose_bf16(const float* __restrict__ W,
                                                        u16* __restrict__ Wt, int K, int N) {
  __shared__ float tile[32][33];
  int n0 = blockIdx.x * 32, k0 = blockIdx.y * 32;
  int tx = threadIdx.x & 31, ty = threadIdx.x >> 5;
  #pragma unroll
  for (int r = ty; r < 32; r += 8) tile[r][tx] = W[(size_t)(k0 + r) * N + n0 + tx];
  __syncthreads();
  #pragma unroll
  for (int r = ty; r < 32; r += 8) Wt[(size_t)(n0 + r) * K + k0 + tx] = f2bf(tile[tx][r]);
}

// ---------- fp32 -> bf16 elementwise (vectorized) ----------
__global__ __launch_bounds__(256) void k_f2bf4(const float4* __restrict__ in,
                                               ushort4* __restrict__ out, int n4) {
  int i = blockIdx.x * 256 + threadIdx.x;
  if (i >= n4) return;
  float4 v = in[i];
  ushort4 o;
  o.x = f2bf(v.x); o.y = f2bf(v.y); o.z = f2bf(v.z); o.w = f2bf(v.w);
  out[i] = o;
}

// ---------- RoPE cos/sin table: [S_LEN][32] ----------
__global__ __launch_bounds__(256) void k_rope_table(float* __restrict__ cosT,
                                                    float* __restrict__ sinT) {
  int idx = blockIdx.x * 256 + threadIdx.x;
  if (idx >= S_LEN * 32) return;
  int s = idx >> 5, i = idx & 31;
  float inv = powf(10000.f, -(float)(2 * i) / 64.f);
  float ang = (float)s * inv;
  cosT[idx] = cosf(ang);
  sinT[idx] = sinf(ang);
}

// ---------- mask tile flags: 0 = all pass (>=0.1), 1 = mixed/masked ----------
__global__ __launch_bounds__(256) void k_mask_flags(const float* __restrict__ mask,
                                                    unsigned char* __restrict__ flags) {
  int kt = blockIdx.x, qt = blockIdx.y;
  const float* mp = mask + (size_t)(qt * 64) * S_LEN + kt * 64;
  int tr = threadIdx.x >> 2;
  int tc = (threadIdx.x & 3) * 16;
  int ok = 1;
  #pragma unroll
  for (int c = 0; c < 16; c += 4) {
    float4 v = *(const float4*)(mp + (size_t)tr * S_LEN + tc + c);
    ok &= (v.x >= 0.1f) & (v.y >= 0.1f) & (v.z >= 0.1f) & (v.w >= 0.1f);
  }
  ok = __all(ok) ? 1 : 0;
  __shared__ int sh[4];
  if ((threadIdx.x & 63) == 0) sh[threadIdx.x >> 6] = ok;
  __syncthreads();
  if (threadIdx.x == 0) flags[qt * 32 + kt] = (sh[0] & sh[1] & sh[2] & sh[3]) ? 0 : 1;
}

// ---------- m97-structure bf16 GEMM: C = A(MxK) @ Bt(NxK)^T + bias [+epilogue] ----------
enum { EPI_F32 = 0, EPI_ADD_F32 = 1, EPI_RELU_BF16 = 2 };

template <int EPI>
__global__ __launch_bounds__(256) void k_gemm(const u16* __restrict__ A, const u16* __restrict__ Bt,
                                              const float* __restrict__ bias,
                                              const float* __restrict__ resid,
                                              float* __restrict__ Cf, u16* __restrict__ Cb,
                                              int M, int N, int K, int ldc) {
  __shared__ __attribute__((aligned(16))) u16 As[128 * 32];
  __shared__ __attribute__((aligned(16))) u16 Bs[128 * 32];
  int m0 = blockIdx.y * 128, n0 = blockIdx.x * 128;
  int tid = threadIdx.x;
  int lane = tid & 63, w = tid >> 6;
  int wm = (w >> 1) * 64, wn = (w & 1) * 64;
  int l15 = lane & 15, l4 = lane >> 4;

  f32x4 acc[4][4] = {};

  for (int k0 = 0; k0 < K; k0 += 32) {
    __syncthreads();
    #pragma unroll
    for (int i = 0; i < 2; ++i) {
      int sl = i * 256 + w * 64;
      int sg = sl + lane;
      const u16* ga = A + (size_t)(m0 + (sg >> 2)) * K + k0 + (sg & 3) * 8;
      gload_lds16(ga, &As[sl * 8]);
      const u16* gb = Bt + (size_t)(n0 + (sg >> 2)) * K + k0 + (sg & 3) * 8;
      gload_lds16(gb, &Bs[sl * 8]);
    }
    __syncthreads();

    bf16x8 af[4], bfr[4];
    #pragma unroll
    for (int i = 0; i < 4; ++i)
      af[i] = *(const bf16x8*)&As[(wm + i * 16 + l15) * 32 + l4 * 8];
    #pragma unroll
    for (int j = 0; j < 4; ++j)
      bfr[j] = *(const bf16x8*)&Bs[(wn + j * 16 + l15) * 32 + l4 * 8];
    #pragma unroll
    for (int i = 0; i < 4; ++i)
      #pragma unroll
      for (int j = 0; j < 4; ++j)
        acc[i][j] = __builtin_amdgcn_mfma_f32_16x16x32_bf16(af[i], bfr[j], acc[i][j], 0, 0, 0);
  }

  #pragma unroll
  for (int i = 0; i < 4; ++i) {
    #pragma unroll
    for (int j = 0; j < 4; ++j) {
      int col = n0 + wn + j * 16 + l15;
      float bv = bias[col];
      #pragma unroll
      for (int r = 0; r < 4; ++r) {
        int m = m0 + wm + i * 16 + l4 * 4 + r;
        float v = acc[i][j][r] + bv;
        size_t o = (size_t)m * ldc + col;
        if (EPI == EPI_F32) Cf[o] = v;
        else if (EPI == EPI_ADD_F32) Cf[o] = v + resid[o];
        else Cb[o] = f2bf(fmaxf(v, 0.f));
      }
    }
  }
}

// ---------- RoPE + head-split; Q pre-scaled by 1/sqrt(HD) (exact pow2) ----------
__global__ __launch_bounds__(256) void k_rope_heads(const float* __restrict__ QKV,
                                                    const float* __restrict__ cosT,
                                                    const float* __restrict__ sinT,
                                                    u16* __restrict__ Qh, u16* __restrict__ Kh,
                                                    u16* __restrict__ Vt) {
  int idx = blockIdx.x * 256 + threadIdx.x;
  if (idx >= MROWS * 512) return;
  int m = idx >> 9, c2 = idx & 511;
  int h = c2 >> 5, i = c2 & 31, d = 2 * i;
  int s = m >> 1, b = m & 1;
  int bh = b * NH + h;
  size_t base = (size_t)m * 3072 + h * 64 + d;
  float q0 = QKV[base], q1 = QKV[base + 1];
  float k0 = QKV[base + 1024], k1 = QKV[base + 1025];
  float v0 = QKV[base + 2048], v1 = QKV[base + 2049];
  float c = cosT[s * 32 + i], sn = sinT[s * 32 + i];
  size_t ho = ((size_t)bh * S_LEN + s) * 64 + d;
  Qh[ho]     = f2bf((q0 * c - q1 * sn) * 0.125f);
  Qh[ho + 1] = f2bf((q1 * c + q0 * sn) * 0.125f);
  Kh[ho]     = f2bf(k0 * c - k1 * sn);
  Kh[ho + 1] = f2bf(k1 * c + k0 * sn);
  size_t vo = ((size_t)bh * 64 + d) * S_LEN + s;
  Vt[vo] = f2bf(v0);
  Vt[vo + S_LEN] = f2bf(v1);
}

// ---------- flash attention: KVB=128, XOR-swizzled LDS, mask tile-flags ----------
// Ks [128 key][64 d]   u16, row = 8 slots of 16B,  read slot ^= (row&7)
// Vs [64 d][128 key]   u16, row = 16 slots of 16B, read slot ^= (row&15)
// Ps per-wave [16 q][128 key] u16, 16 slots/row,   slot ^= row
__global__ __launch_bounds__(256) void k_attn(const u16* __restrict__ Qh, const u16* __restrict__ Kh,
                                              const u16* __restrict__ Vt,
                                              const float* __restrict__ mask,
                                              const unsigned char* __restrict__ flags,
                                              u16* __restrict__ Out) {
  __shared__ __attribute__((aligned(16))) u16 Ks[KVB * 64];
  __shared__ __attribute__((aligned(16))) u16 Vs[64 * KVB];
  __shared__ __attribute__((aligned(16))) u16 Ps[4 * 16 * KVB];
  int bh = blockIdx.y;
  int q0 = blockIdx.x * 64;
  int b = bh >> 4, h = bh & 15;
  int tid = threadIdx.x, lane = tid & 63, w = tid >> 6;
  int l15 = lane & 15, l4 = lane >> 4;
  int qt = q0 >> 6;

  int qrow = q0 + w * 16 + l15;
  const u16* qp = Qh + ((size_t)bh * S_LEN + qrow) * 64 + l4 * 8;
  bf16x8 qa0 = *(const bf16x8*)qp;
  bf16x8 qa1 = *(const bf16x8*)(qp + 32);

  float m_run[4], l_run[4];
  f32x4 o_acc[4] = {};
  #pragma unroll
  for (int r = 0; r < 4; ++r) { m_run[r] = -1e30f; l_run[r] = 0.f; }

  for (int kv0 = 0; kv0 < S_LEN; kv0 += KVB) {
    __syncthreads();  // prior iter's PV reads of Vs done before restage
    #pragma unroll
    for (int i = 0; i < 4; ++i) {
      int sl = i * 256 + w * 64;
      int sg = sl + lane;
      int kr = sg >> 3, kslot = sg & 7;
      const u16* gk = Kh + ((size_t)bh * S_LEN + kv0 + kr) * 64 + (kslot ^ (kr & 7)) * 8;
      gload_lds16(gk, &Ks[sl * 8]);
      int vr = sg >> 4, vslot = sg & 15;
      const u16* gv = Vt + ((size_t)bh * 64 + vr) * S_LEN + kv0 + ((vslot ^ (vr & 15))) * 8;
      gload_lds16(gv, &Vs[sl * 8]);
    }
    __syncthreads();  // drains vmcnt -> tiles ready

    // S = Q @ K^T  (16 q-rows x 128 keys per wave)
    f32x4 sc[8] = {};
    #pragma unroll
    for (int ks = 0; ks < 2; ++ks) {
      bf16x8 qa = ks ? qa1 : qa0;
      #pragma unroll
      for (int j = 0; j < 8; ++j) {
        int row = j * 16 + l15;
        bf16x8 kb = *(const bf16x8*)&Ks[row * 64 + ((ks * 4 + l4) ^ (row & 7)) * 8];
        sc[j] = __builtin_amdgcn_mfma_f32_16x16x32_bf16(qa, kb, sc[j], 0, 0, 0);
      }
    }

    int kt2 = kv0 >> 6;
    int fl = flags[qt * 32 + kt2] | flags[qt * 32 + kt2 + 1];

    // online softmax (row of quadrant = l4*4+r; reduce across 16-lane l15 group)
    #pragma unroll
    for (int r = 0; r < 4; ++r) {
      if (fl) {  // slow path: per-element mask (wave-uniform branch; off for all-pass)
        int qg = q0 + w * 16 + l4 * 4 + r;
        #pragma unroll
        for (int j = 0; j < 8; ++j)
          if (mask[(size_t)qg * S_LEN + kv0 + j * 16 + l15] < 0.1f) sc[j][r] = -1e30f;
      }
      float mx = m_run[r];
      #pragma unroll
      for (int j = 0; j < 8; ++j) mx = fmaxf(mx, sc[j][r]);
      #pragma unroll
      for (int off = 8; off >= 1; off >>= 1) mx = fmaxf(mx, __shfl_xor(mx, off, 64));
      float corr = __expf(m_run[r] - mx);
      float rs = 0.f;
      #pragma unroll
      for (int j = 0; j < 8; ++j) {
        float p = __expf(sc[j][r] - mx);
        sc[j][r] = p;
        rs += p;
      }
      #pragma unroll
      for (int off = 8; off >= 1; off >>= 1) rs += __shfl_xor(rs, off, 64);
      m_run[r] = mx;
      l_run[r] = l_run[r] * corr + rs;
      #pragma unroll
      for (int jd = 0; jd < 4; ++jd) o_acc[jd][r] *= corr;
    }

    // P (C-layout) -> LDS (swizzled) -> A-frag layout for PV
    #pragma unroll
    for (int j = 0; j < 8; ++j) {
      #pragma unroll
      for (int r = 0; r < 4; ++r) {
        int row = l4 * 4 + r;
        int col = j * 16 + l15;
        int slot = col >> 3;
        Ps[w * 2048 + row * 128 + (slot ^ row) * 8 + (col & 7)] = f2bf(sc[j][r]);
      }
    }
    __syncthreads();

    // O += P @ V
    #pragma unroll
    for (int ks2 = 0; ks2 < 4; ++ks2) {
      bf16x8 pa = *(const bf16x8*)&Ps[w * 2048 + l15 * 128 + ((ks2 * 4 + l4) ^ l15) * 8];
      #pragma unroll
      for (int jd = 0; jd < 4; ++jd) {
        int vrow = jd * 16 + l15;
        bf16x8 vb = *(const bf16x8*)&Vs[vrow * 128 + ((ks2 * 4 + l4) ^ (vrow & 15)) * 8];
        o_acc[jd] = __builtin_amdgcn_mfma_f32_16x16x32_bf16(pa, vb, o_acc[jd], 0, 0, 0);
      }
    }
  }

  // write attn output in (m, d_model) layout for the O-projection GEMM
  #pragma unroll
  for (int jd = 0; jd < 4; ++jd) {
    #pragma unroll
    for (int r = 0; r < 4; ++r) {
      int qg = q0 + w * 16 + l4 * 4 + r;
      int mrow = qg * 2 + b;
      float ov = o_acc[jd][r] / l_run[r];
      Out[(size_t)mrow * DM + h * 64 + jd * 16 + l15] = f2bf(ov);
    }
  }
}

// ---------- LayerNorm over rows of 1024; optional bf16 copy ----------
__device__ __forceinline__ float wave_sum(float v) {
  #pragma unroll
  for (int off = 32; off >= 1; off >>= 1) v += __shfl_xor(v, off, 64);
  return v;
}

template <int WB>
__global__ __launch_bounds__(256) void k_layernorm(const float* __restrict__ X,
                                                   const float* __restrict__ gw,
                                                   const float* __restrict__ bw,
                                                   float* __restrict__ Yf, u16* __restrict__ Yb) {
  int m = blockIdx.x;
  int tid = threadIdx.x, lane = tid & 63, w = tid >> 6;
  __shared__ float part[4];
  __shared__ float shv[2];
  float4 v = ((const float4*)(X + (size_t)m * DM))[tid];
  float s = wave_sum(v.x + v.y + v.z + v.w);
  if (lane == 0) part[w] = s;
  __syncthreads();
  if (tid == 0) shv[0] = (part[0] + part[1] + part[2] + part[3]) * (1.f / DM);
  __syncthreads();
  float mu = shv[0];
  float d0 = v.x - mu, d1 = v.y - mu, d2 = v.z - mu, d3 = v.w - mu;
  float q = wave_sum(d0 * d0 + d1 * d1 + d2 * d2 + d3 * d3);
  if (lane == 0) part[w] = q;
  __syncthreads();
  if (tid == 0) shv[1] = rsqrtf((part[0] + part[1] + part[2] + part[3]) * (1.f / DM) + 1e-5f);
  __syncthreads();
  float rstd = shv[1];
  float4 g4 = ((const float4*)gw)[tid];
  float4 b4 = ((const float4*)bw)[tid];
  float y0 = d0 * rstd * g4.x + b4.x;
  float y1 = d1 * rstd * g4.y + b4.y;
  float y2 = d2 * rstd * g4.z + b4.z;
  float y3 = d3 * rstd * g4.w + b4.w;
  ((float4*)(Yf + (size_t)m * DM))[tid] = make_float4(y0, y1, y2, y3);
  if (WB) {
    ushort4 o;
    o.x = f2bf(y0); o.y = f2bf(y1); o.z = f2bf(y2); o.w = f2bf(y3);
    ((ushort4*)(Yb + (size_t)m * DM))[tid] = o;
  }
}

extern "C" void kernel_launch(void* const* d_in, const int* in_sizes, int n_in,
                              void* d_out, int out_size, void* d_ws, size_t ws_size,
                              hipStream_t stream) {
  (void)in_sizes; (void)n_in; (void)out_size; (void)ws_size;
  const float* src  = (const float*)d_in[0];
  const float* mask = (const float*)d_in[1];
  const float* Wq = (const float*)d_in[2];  const float* bq  = (const float*)d_in[3];
  const float* Wk = (const float*)d_in[4];  const float* bk  = (const float*)d_in[5];
  const float* Wv = (const float*)d_in[6];  const float* bv  = (const float*)d_in[7];
  const float* Wo = (const float*)d_in[8];  const float* bo  = (const float*)d_in[9];
  const float* W1 = (const float*)d_in[10]; const float* b1  = (const float*)d_in[11];
  const float* W2 = (const float*)d_in[12]; const float* b2  = (const float*)d_in[13];
  const float* g1 = (const float*)d_in[14]; const float* be1 = (const float*)d_in[15];
  const float* g2 = (const float*)d_in[16]; const float* be2 = (const float*)d_in[17];
  float* out = (float*)d_out;

  char* base = (char*)d_ws;
  size_t off = 0;
  auto carve = [&](size_t bytes) -> void* {
    void* r = base + off;
    off += (bytes + 255) & ~(size_t)255;
    return r;
  };
  u16* Wq_t = (u16*)carve(2ull * 1024 * 1024);
  u16* Wk_t = (u16*)carve(2ull * 1024 * 1024);
  u16* Wv_t = (u16*)carve(2ull * 1024 * 1024);
  u16* Wo_t = (u16*)carve(2ull * 1024 * 1024);
  u16* W1_t = (u16*)carve(2ull * 4096 * 1024);
  u16* W2_t = (u16*)carve(2ull * 1024 * 4096);
  u16* Xbf  = (u16*)carve(2ull * 4096 * 1024);
  float* cosT = (float*)carve(4ull * 2048 * 32);
  float* sinT = (float*)carve(4ull * 2048 * 32);
  unsigned char* mflags = (unsigned char*)carve(1024);
  u16* attn_out = (u16*)carve(2ull * 4096 * 1024);
  float* resid1 = (float*)carve(4ull * 4096 * 1024);
  float* QKV = (float*)carve(4ull * 4096 * 3072);       // 48MB; reused after rope_heads
  u16* Qh = (u16*)carve(2ull * 32 * 2048 * 64);
  u16* Kh = (u16*)carve(2ull * 32 * 2048 * 64);
  u16* Vt = (u16*)carve(2ull * 32 * 2048 * 64);
  // aliases (lifetimes: QKV dead after rope_heads; Qh/Kh/Vt dead after attn)
  u16* ff1 = (u16*)QKV;                                  // 32MB
  float* resid2 = (float*)((char*)QKV + 2ull * 4096 * 4096);  // +32MB, 16MB
  float* src2f = (float*)Qh;                             // 16MB (Qh+Kh)
  u16* src2b = (u16*)Vt;                                 // 8MB

  dim3 blk(256);
  k_transpose_bf16<<<dim3(32, 32), blk, 0, stream>>>(Wq, Wq_t, 1024, 1024);
  k_transpose_bf16<<<dim3(32, 32), blk, 0, stream>>>(Wk, Wk_t, 1024, 1024);
  k_transpose_bf16<<<dim3(32, 32), blk, 0, stream>>>(Wv, Wv_t, 1024, 1024);
  k_transpose_bf16<<<dim3(32, 32), blk, 0, stream>>>(Wo, Wo_t, 1024, 1024);
  k_transpose_bf16<<<dim3(128, 32), blk, 0, stream>>>(W1, W1_t, 1024, 4096);
  k_transpose_bf16<<<dim3(32, 128), blk, 0, stream>>>(W2, W2_t, 4096, 1024);
  k_f2bf4<<<dim3(4096), blk, 0, stream>>>((const float4*)src, (ushort4*)Xbf, 4096 * 1024 / 4);
  k_rope_table<<<dim3(256), blk, 0, stream>>>(cosT, sinT);
  k_mask_flags<<<dim3(32, 32), blk, 0, stream>>>(mask, mflags);
  // QKV projections (fp32 out, bias)
  k_gemm<EPI_F32><<<dim3(8, 32), blk, 0, stream>>>(Xbf, Wq_t, bq, nullptr, QKV + 0,    nullptr, 4096, 1024, 1024, 3072);
  k_gemm<EPI_F32><<<dim3(8, 32), blk, 0, stream>>>(Xbf, Wk_t, bk, nullptr, QKV + 1024, nullptr, 4096, 1024, 1024, 3072);
  k_gemm<EPI_F32><<<dim3(8, 32), blk, 0, stream>>>(Xbf, Wv_t, bv, nullptr, QKV + 2048, nullptr, 4096, 1024, 1024, 3072);
  k_rope_heads<<<dim3(MROWS * 512 / 256), blk, 0, stream>>>(QKV, cosT, sinT, Qh, Kh, Vt);
  k_attn<<<dim3(32, 32), blk, 0, stream>>>(Qh, Kh, Vt, mask, mflags, attn_out);
  k_gemm<EPI_ADD_F32><<<dim3(8, 32), blk, 0, stream>>>(attn_out, Wo_t, bo, src, resid1, nullptr, 4096, 1024, 1024, 1024);
  k_layernorm<1><<<dim3(4096), blk, 0, stream>>>(resid1, g1, be1, src2f, src2b);
  k_gemm<EPI_RELU_BF16><<<dim3(32, 32), blk, 0, stream>>>(src2b, W1_t, b1, nullptr, nullptr, ff1, 4096, 4096, 1024, 4096);
  k_gemm<EPI_ADD_F32><<<dim3(8, 32), blk, 0, stream>>>(ff1, W2_t, b2, src2f, resid2, nullptr, 4096, 1024, 4096, 1024);
  k_layernorm<0><<<dim3(4096), blk, 0, stream>>>(resid2, g2, be2, out, nullptr);
}

// Round 4
// 363.774 us; speedup vs baseline: 1.3165x; 1.2125x over previous
//
#include <hip/hip_runtime.h>
#include <math.h>

#define S_LEN 2048
#define DM 1024
#define NH 16
#define HD 64
#define DFF 4096
#define MROWS 4096  // S_LEN * 2 batch

typedef unsigned short u16;
typedef __attribute__((ext_vector_type(8))) __bf16 bf16x8;
typedef __attribute__((ext_vector_type(4))) float f32x4;
typedef __attribute__((ext_vector_type(16))) float f32x16;
typedef __attribute__((ext_vector_type(4))) int int32x4;

__device__ __forceinline__ u16 f2bf(float f) {
  unsigned u = __float_as_uint(f);
  unsigned r = (u + 0x7fffu + ((u >> 16) & 1u)) >> 16;  // RNE
  return (u16)r;
}

__device__ __forceinline__ unsigned cvtpk_bf16(float lo, float hi) {
  unsigned r;
  asm("v_cvt_pk_bf16_f32 %0, %1, %2" : "=v"(r) : "v"(lo), "v"(hi));
  return r;
}

__device__ __forceinline__ void gload_lds16(const void* g, void* l) {
  __builtin_amdgcn_global_load_lds((__attribute__((address_space(1))) void*)g,
                                   (__attribute__((address_space(3))) void*)l, 16, 0, 0);
}

// ---------- transpose + fp32->bf16 weights: W (K x N) -> Wt (N x K) ----------
__global__ __launch_bounds__(256) void k_transpose_bf16(const float* __restrict__ W,
                                                        u16* __restrict__ Wt, int K, int N) {
  __shared__ float tile[32][33];
  int n0 = blockIdx.x * 32, k0 = blockIdx.y * 32;
  int tx = threadIdx.x & 31, ty = threadIdx.x >> 5;
  #pragma unroll
  for (int r = ty; r < 32; r += 8) tile[r][tx] = W[(size_t)(k0 + r) * N + n0 + tx];
  __syncthreads();
  #pragma unroll
  for (int r = ty; r < 32; r += 8) Wt[(size_t)(n0 + r) * K + k0 + tx] = f2bf(tile[tx][r]);
}

__global__ __launch_bounds__(256) void k_f2bf4(const float4* __restrict__ in,
                                               ushort4* __restrict__ out, int n4) {
  int i = blockIdx.x * 256 + threadIdx.x;
  if (i >= n4) return;
  float4 v = in[i];
  ushort4 o;
  o.x = f2bf(v.x); o.y = f2bf(v.y); o.z = f2bf(v.z); o.w = f2bf(v.w);
  out[i] = o;
}

__global__ __launch_bounds__(256) void k_rope_table(float* __restrict__ cosT,
                                                    float* __restrict__ sinT) {
  int idx = blockIdx.x * 256 + threadIdx.x;
  if (idx >= S_LEN * 32) return;
  int s = idx >> 5, i = idx & 31;
  float inv = powf(10000.f, -(float)(2 * i) / 64.f);
  float ang = (float)s * inv;
  cosT[idx] = cosf(ang);
  sinT[idx] = sinf(ang);
}

__global__ __launch_bounds__(256) void k_cat3(const float* __restrict__ a, const float* __restrict__ b,
                                              const float* __restrict__ c, float* __restrict__ o) {
  int i = blockIdx.x * 256 + threadIdx.x;
  if (i >= 3072) return;
  o[i] = i < 1024 ? a[i] : (i < 2048 ? b[i - 1024] : c[i - 2048]);
}

// ---------- mask tile flags: 0 = all pass (>=0.1), 1 = mixed/masked ----------
__global__ __launch_bounds__(256) void k_mask_flags(const float* __restrict__ mask,
                                                    unsigned char* __restrict__ flags) {
  int kt = blockIdx.x, qt = blockIdx.y;
  const float* mp = mask + (size_t)(qt * 64) * S_LEN + kt * 64;
  int tr = threadIdx.x >> 2;
  int tc = (threadIdx.x & 3) * 16;
  int ok = 1;
  #pragma unroll
  for (int c = 0; c < 16; c += 4) {
    float4 v = *(const float4*)(mp + (size_t)tr * S_LEN + tc + c);
    ok &= (v.x >= 0.1f) & (v.y >= 0.1f) & (v.z >= 0.1f) & (v.w >= 0.1f);
  }
  ok = __all(ok) ? 1 : 0;
  __shared__ int sh[4];
  if ((threadIdx.x & 63) == 0) sh[threadIdx.x >> 6] = ok;
  __syncthreads();
  if (threadIdx.x == 0) flags[qt * 32 + kt] = (sh[0] & sh[1] & sh[2] & sh[3]) ? 0 : 1;
}

// ---------- m97-structure bf16 GEMM ----------
enum { EPI_F32 = 0, EPI_ADD_F32 = 1, EPI_RELU_BF16 = 2 };

template <int EPI>
__global__ __launch_bounds__(256) void k_gemm(const u16* __restrict__ A, const u16* __restrict__ Bt,
                                              const float* __restrict__ bias,
                                              const float* __restrict__ resid,
                                              float* __restrict__ Cf, u16* __restrict__ Cb,
                                              int M, int N, int K, int ldc) {
  __shared__ __attribute__((aligned(16))) u16 As[128 * 32];
  __shared__ __attribute__((aligned(16))) u16 Bs[128 * 32];
  int m0 = blockIdx.y * 128, n0 = blockIdx.x * 128;
  int tid = threadIdx.x;
  int lane = tid & 63, w = tid >> 6;
  int wm = (w >> 1) * 64, wn = (w & 1) * 64;
  int l15 = lane & 15, l4 = lane >> 4;

  f32x4 acc[4][4] = {};

  for (int k0 = 0; k0 < K; k0 += 32) {
    __syncthreads();
    #pragma unroll
    for (int i = 0; i < 2; ++i) {
      int sl = i * 256 + w * 64;
      int sg = sl + lane;
      const u16* ga = A + (size_t)(m0 + (sg >> 2)) * K + k0 + (sg & 3) * 8;
      gload_lds16(ga, &As[sl * 8]);
      const u16* gb = Bt + (size_t)(n0 + (sg >> 2)) * K + k0 + (sg & 3) * 8;
      gload_lds16(gb, &Bs[sl * 8]);
    }
    __syncthreads();

    bf16x8 af[4], bfr[4];
    #pragma unroll
    for (int i = 0; i < 4; ++i)
      af[i] = *(const bf16x8*)&As[(wm + i * 16 + l15) * 32 + l4 * 8];
    #pragma unroll
    for (int j = 0; j < 4; ++j)
      bfr[j] = *(const bf16x8*)&Bs[(wn + j * 16 + l15) * 32 + l4 * 8];
    #pragma unroll
    for (int i = 0; i < 4; ++i)
      #pragma unroll
      for (int j = 0; j < 4; ++j)
        acc[i][j] = __builtin_amdgcn_mfma_f32_16x16x32_bf16(af[i], bfr[j], acc[i][j], 0, 0, 0);
  }

  #pragma unroll
  for (int i = 0; i < 4; ++i) {
    #pragma unroll
    for (int j = 0; j < 4; ++j) {
      int col = n0 + wn + j * 16 + l15;
      float bv = bias[col];
      #pragma unroll
      for (int r = 0; r < 4; ++r) {
        int m = m0 + wm + i * 16 + l4 * 4 + r;
        float v = acc[i][j][r] + bv;
        size_t o = (size_t)m * ldc + col;
        if (EPI == EPI_F32) Cf[o] = v;
        else if (EPI == EPI_ADD_F32) Cf[o] = v + resid[o];
        else Cb[o] = f2bf(fmaxf(v, 0.f));
      }
    }
  }
}

// ---------- RoPE + head-split; Q pre-scaled by log2(e)/sqrt(HD) (exp2 domain) ----------
#define QSCALE 0.180336881f
__global__ __launch_bounds__(256) void k_rope_heads(const float* __restrict__ QKV,
                                                    const float* __restrict__ cosT,
                                                    const float* __restrict__ sinT,
                                                    u16* __restrict__ Qh, u16* __restrict__ Kh,
                                                    u16* __restrict__ Vt) {
  int idx = blockIdx.x * 256 + threadIdx.x;
  if (idx >= MROWS * 512) return;
  int m = idx >> 9, c2 = idx & 511;
  int h = c2 >> 5, i = c2 & 31, d = 2 * i;
  int s = m >> 1, b = m & 1;
  int bh = b * NH + h;
  size_t base = (size_t)m * 3072 + h * 64 + d;
  float q0 = QKV[base], q1 = QKV[base + 1];
  float k0 = QKV[base + 1024], k1 = QKV[base + 1025];
  float v0 = QKV[base + 2048], v1 = QKV[base + 2049];
  float c = cosT[s * 32 + i], sn = sinT[s * 32 + i];
  size_t ho = ((size_t)bh * S_LEN + s) * 64 + d;
  Qh[ho]     = f2bf((q0 * c - q1 * sn) * QSCALE);
  Qh[ho + 1] = f2bf((q1 * c + q0 * sn) * QSCALE);
  Kh[ho]     = f2bf(k0 * c - k1 * sn);
  Kh[ho + 1] = f2bf(k1 * c + k0 * sn);
  size_t vo = ((size_t)bh * 64 + d) * S_LEN + s;
  Vt[vo] = f2bf(v0);
  Vt[vo + S_LEN] = f2bf(v1);
}

// ---------- flash attention: swapped-QK^T 32x32x16, in-register softmax ----------
// Block: 4 waves x 32 q-rows = 128 q. KV staged 128, computed as 2x64 subtiles.
// Ks [128 key][64 d]  u16, 8 slots/row,  slot ^= (row&7)
// Vs [64 d][128 key]  u16, 16 slots/row, slot ^= (row&15)
__global__ __launch_bounds__(256) void k_attn(const u16* __restrict__ Qh, const u16* __restrict__ Kh,
                                              const u16* __restrict__ Vt,
                                              const float* __restrict__ mask,
                                              const unsigned char* __restrict__ flags,
                                              u16* __restrict__ Out) {
  __shared__ __attribute__((aligned(16))) u16 Ks[128 * 64];
  __shared__ __attribute__((aligned(16))) u16 Vs[64 * 128];
  int bh = blockIdx.y;
  int q0 = blockIdx.x * 128;
  int b = bh >> 4, h = bh & 15;
  int tid = threadIdx.x, lane = tid & 63, w = tid >> 6;
  int l31 = lane & 31, l5 = lane >> 5;

  int qrow = q0 + w * 32 + l31;
  int qt = qrow >> 6;  // wave-uniform (w*32 within 64-aligned span)

  // Q B-fragments: B[k=d][col=q]: lane holds Q[qrow][dc*16 + l5*8 .. +7]
  bf16x8 qf[4];
  {
    const u16* qp = Qh + ((size_t)bh * S_LEN + qrow) * 64 + l5 * 8;
    #pragma unroll
    for (int dc = 0; dc < 4; ++dc) qf[dc] = *(const bf16x8*)(qp + dc * 16);
  }

  float m_run = -1e30f, l_run = 0.f;
  f32x16 oA = {}, oB = {};  // O^T: d = db*32 + (reg&3)+8*(reg>>2)+4*l5, q = l31

  for (int kv0 = 0; kv0 < S_LEN; kv0 += 128) {
    __syncthreads();  // prior subtile's PV reads done before restage
    #pragma unroll
    for (int i = 0; i < 4; ++i) {
      int sid = i * 256 + tid;
      int kr = sid >> 3, kslot = sid & 7;
      gload_lds16(Kh + ((size_t)bh * S_LEN + kv0 + kr) * 64 + (kslot ^ (kr & 7)) * 8,
                  &Ks[(i * 256 + w * 64) * 8 + (lane & 63) * 0 + (sid - (i * 256 + w * 64)) * 8]);
      int vr = sid >> 4, vslot = sid & 15;
      gload_lds16(Vt + ((size_t)bh * 64 + vr) * S_LEN + kv0 + ((vslot ^ (vr & 15))) * 8,
                  &Vs[sid * 8]);
    }
    __syncthreads();

    #pragma unroll
    for (int ksub = 0; ksub < 2; ++ksub) {
      int koff = ksub * 64;
      // S^T = K @ Q^T : two 32-key blocks
      f32x16 sA = {}, sB = {};
      #pragma unroll
      for (int dc = 0; dc < 4; ++dc) {
        int r0 = koff + l31;
        int r1 = koff + 32 + l31;
        int slot = (dc * 2 + l5) ^ (l31 & 7);
        bf16x8 ka0 = *(const bf16x8*)&Ks[r0 * 64 + slot * 8];
        bf16x8 ka1 = *(const bf16x8*)&Ks[r1 * 64 + slot * 8];
        sA = __builtin_amdgcn_mfma_f32_32x32x16_bf16(ka0, qf[dc], sA, 0, 0, 0);
        sB = __builtin_amdgcn_mfma_f32_32x32x16_bf16(ka1, qf[dc], sB, 0, 0, 0);
      }

      // mask slow path (wave-uniform branch; all-pass tiles skip)
      int fl = flags[qt * 32 + ((kv0 + koff) >> 6)];
      if (fl) {
        const float* mrow = mask + (size_t)qrow * S_LEN + kv0 + koff;
        #pragma unroll
        for (int r = 0; r < 16; ++r) {
          int key = (r & 3) + 8 * (r >> 2) + 4 * l5;
          if (mrow[key] < 0.1f) sA[r] = -1e30f;
          if (mrow[key + 32] < 0.1f) sB[r] = -1e30f;
        }
      }

      // in-register online softmax (q-row local; halves synced via xor-32)
      float pm = m_run;
      #pragma unroll
      for (int r = 0; r < 16; ++r) pm = fmaxf(pm, fmaxf(sA[r], sB[r]));
      pm = fmaxf(pm, __shfl_xor(pm, 32, 64));
      if (!__all(pm <= m_run + 8.f)) {  // defer-max (log2 units)
        float corr = __builtin_amdgcn_exp2f(m_run - pm);
        m_run = pm;
        l_run *= corr;
        #pragma unroll
        for (int r = 0; r < 16; ++r) { oA[r] *= corr; oB[r] *= corr; }
      }
      float ps = 0.f;
      #pragma unroll
      for (int r = 0; r < 16; ++r) {
        sA[r] = __builtin_amdgcn_exp2f(sA[r] - m_run);
        sB[r] = __builtin_amdgcn_exp2f(sB[r] - m_run);
        ps += sA[r] + sB[r];
      }
      l_run += ps;

      // P^T -> B-frags via cvt_pk + permlane32_swap; PV: O^T += V^T @ P^T
      #pragma unroll
      for (int kh = 0; kh < 2; ++kh) {
        f32x16 s = kh ? sB : sA;
        #pragma unroll
        for (int c = 0; c < 2; ++c) {
          int base = c * 8;
          unsigned u0 = cvtpk_bf16(s[base + 0], s[base + 1]);
          unsigned u1 = cvtpk_bf16(s[base + 2], s[base + 3]);
          unsigned u2 = cvtpk_bf16(s[base + 4], s[base + 5]);
          unsigned u3 = cvtpk_bf16(s[base + 6], s[base + 7]);
          asm volatile("v_permlane32_swap_b32 %0, %1" : "+v"(u0), "+v"(u2));
          asm volatile("v_permlane32_swap_b32 %0, %1" : "+v"(u1), "+v"(u3));
          int32x4 wds = {(int)u0, (int)u1, (int)u2, (int)u3};
          bf16x8 pb = *(bf16x8*)&wds;
          int kslot = ksub * 8 + (kh * 2 + c) * 2 + l5;
          int vr0 = l31, vr1 = 32 + l31;
          bf16x8 va0 = *(const bf16x8*)&Vs[vr0 * 128 + (kslot ^ (vr0 & 15)) * 8];
          bf16x8 va1 = *(const bf16x8*)&Vs[vr1 * 128 + (kslot ^ (vr1 & 15)) * 8];
          oA = __builtin_amdgcn_mfma_f32_32x32x16_bf16(va0, pb, oA, 0, 0, 0);
          oB = __builtin_amdgcn_mfma_f32_32x32x16_bf16(va1, pb, oB, 0, 0, 0);
        }
      }
    }
  }

  float l_tot = l_run + __shfl_xor(l_run, 32, 64);
  float inv = 1.f / l_tot;
  int mrow = qrow * 2 + b;
  u16* op = Out + (size_t)mrow * DM + h * 64;
  #pragma unroll
  for (int db = 0; db < 2; ++db) {
    f32x16 o = db ? oB : oA;
    #pragma unroll
    for (int g = 0; g < 4; ++g) {
      int d0 = db * 32 + 8 * g + 4 * l5;
      ushort4 st;
      st.x = f2bf(o[4 * g + 0] * inv);
      st.y = f2bf(o[4 * g + 1] * inv);
      st.z = f2bf(o[4 * g + 2] * inv);
      st.w = f2bf(o[4 * g + 3] * inv);
      *(ushort4*)(op + d0) = st;
    }
  }
}

// ---------- LayerNorm ----------
__device__ __forceinline__ float wave_sum(float v) {
  #pragma unroll
  for (int off = 32; off >= 1; off >>= 1) v += __shfl_xor(v, off, 64);
  return v;
}

template <int WB>
__global__ __launch_bounds__(256) void k_layernorm(const float* __restrict__ X,
                                                   const float* __restrict__ gw,
                                                   const float* __restrict__ bw,
                                                   float* __restrict__ Yf, u16* __restrict__ Yb) {
  int m = blockIdx.x;
  int tid = threadIdx.x, lane = tid & 63, w = tid >> 6;
  __shared__ float part[4];
  __shared__ float shv[2];
  float4 v = ((const float4*)(X + (size_t)m * DM))[tid];
  float s = wave_sum(v.x + v.y + v.z + v.w);
  if (lane == 0) part[w] = s;
  __syncthreads();
  if (tid == 0) shv[0] = (part[0] + part[1] + part[2] + part[3]) * (1.f / DM);
  __syncthreads();
  float mu = shv[0];
  float d0 = v.x - mu, d1 = v.y - mu, d2 = v.z - mu, d3 = v.w - mu;
  float q = wave_sum(d0 * d0 + d1 * d1 + d2 * d2 + d3 * d3);
  if (lane == 0) part[w] = q;
  __syncthreads();
  if (tid == 0) shv[1] = rsqrtf((part[0] + part[1] + part[2] + part[3]) * (1.f / DM) + 1e-5f);
  __syncthreads();
  float rstd = shv[1];
  float4 g4 = ((const float4*)gw)[tid];
  float4 b4 = ((const float4*)bw)[tid];
  float y0 = d0 * rstd * g4.x + b4.x;
  float y1 = d1 * rstd * g4.y + b4.y;
  float y2 = d2 * rstd * g4.z + b4.z;
  float y3 = d3 * rstd * g4.w + b4.w;
  ((float4*)(Yf + (size_t)m * DM))[tid] = make_float4(y0, y1, y2, y3);
  if (WB) {
    ushort4 o;
    o.x = f2bf(y0); o.y = f2bf(y1); o.z = f2bf(y2); o.w = f2bf(y3);
    ((ushort4*)(Yb + (size_t)m * DM))[tid] = o;
  }
}

extern "C" void kernel_launch(void* const* d_in, const int* in_sizes, int n_in,
                              void* d_out, int out_size, void* d_ws, size_t ws_size,
                              hipStream_t stream) {
  (void)in_sizes; (void)n_in; (void)out_size; (void)ws_size;
  const float* src  = (const float*)d_in[0];
  const float* mask = (const float*)d_in[1];
  const float* Wq = (const float*)d_in[2];  const float* bq  = (const float*)d_in[3];
  const float* Wk = (const float*)d_in[4];  const float* bk  = (const float*)d_in[5];
  const float* Wv = (const float*)d_in[6];  const float* bv  = (const float*)d_in[7];
  const float* Wo = (const float*)d_in[8];  const float* bo  = (const float*)d_in[9];
  const float* W1 = (const float*)d_in[10]; const float* b1  = (const float*)d_in[11];
  const float* W2 = (const float*)d_in[12]; const float* b2  = (const float*)d_in[13];
  const float* g1 = (const float*)d_in[14]; const float* be1 = (const float*)d_in[15];
  const float* g2 = (const float*)d_in[16]; const float* be2 = (const float*)d_in[17];
  float* out = (float*)d_out;

  char* base = (char*)d_ws;
  size_t off = 0;
  auto carve = [&](size_t bytes) -> void* {
    void* r = base + off;
    off += (bytes + 255) & ~(size_t)255;
    return r;
  };
  u16* Wq_t = (u16*)carve(2ull * 1024 * 1024);  // NOTE: Wq_t/Wk_t/Wv_t contiguous -> fused N=3072 GEMM
  u16* Wk_t = (u16*)carve(2ull * 1024 * 1024);
  u16* Wv_t = (u16*)carve(2ull * 1024 * 1024);
  u16* Wo_t = (u16*)carve(2ull * 1024 * 1024);
  u16* W1_t = (u16*)carve(2ull * 4096 * 1024);
  u16* W2_t = (u16*)carve(2ull * 1024 * 4096);
  u16* Xbf  = (u16*)carve(2ull * 4096 * 1024);
  float* cosT = (float*)carve(4ull * 2048 * 32);
  float* sinT = (float*)carve(4ull * 2048 * 32);
  float* bqkv = (float*)carve(4ull * 3072);
  unsigned char* mflags = (unsigned char*)carve(1024);
  u16* attn_out = (u16*)carve(2ull * 4096 * 1024);
  float* resid1 = (float*)carve(4ull * 4096 * 1024);
  float* QKV = (float*)carve(4ull * 4096 * 3072);       // 48MB; reused after rope_heads
  u16* Qh = (u16*)carve(2ull * 32 * 2048 * 64);
  u16* Kh = (u16*)carve(2ull * 32 * 2048 * 64);
  u16* Vt = (u16*)carve(2ull * 32 * 2048 * 64);
  // aliases (lifetimes: QKV dead after rope_heads; Qh/Kh/Vt dead after attn)
  u16* ff1 = (u16*)QKV;                                  // 32MB
  float* resid2 = (float*)((char*)QKV + 2ull * 4096 * 4096);  // +32MB, 16MB
  float* src2f = (float*)Qh;                             // 16MB (Qh+Kh)
  u16* src2b = (u16*)Vt;                                 // 8MB

  dim3 blk(256);
  k_transpose_bf16<<<dim3(32, 32), blk, 0, stream>>>(Wq, Wq_t, 1024, 1024);
  k_transpose_bf16<<<dim3(32, 32), blk, 0, stream>>>(Wk, Wk_t, 1024, 1024);
  k_transpose_bf16<<<dim3(32, 32), blk, 0, stream>>>(Wv, Wv_t, 1024, 1024);
  k_transpose_bf16<<<dim3(32, 32), blk, 0, stream>>>(Wo, Wo_t, 1024, 1024);
  k_transpose_bf16<<<dim3(128, 32), blk, 0, stream>>>(W1, W1_t, 1024, 4096);
  k_transpose_bf16<<<dim3(32, 128), blk, 0, stream>>>(W2, W2_t, 4096, 1024);
  k_f2bf4<<<dim3(4096), blk, 0, stream>>>((const float4*)src, (ushort4*)Xbf, 4096 * 1024 / 4);
  k_rope_table<<<dim3(256), blk, 0, stream>>>(cosT, sinT);
  k_cat3<<<dim3(12), blk, 0, stream>>>(bq, bk, bv, bqkv);
  k_mask_flags<<<dim3(32, 32), blk, 0, stream>>>(mask, mflags);
  // fused QKV projection (N=3072)
  k_gemm<EPI_F32><<<dim3(24, 32), blk, 0, stream>>>(Xbf, Wq_t, bqkv, nullptr, QKV, nullptr, 4096, 3072, 1024, 3072);
  k_rope_heads<<<dim3(MROWS * 512 / 256), blk, 0, stream>>>(QKV, cosT, sinT, Qh, Kh, Vt);
  k_attn<<<dim3(16, 32), blk, 0, stream>>>(Qh, Kh, Vt, mask, mflags, attn_out);
  k_gemm<EPI_ADD_F32><<<dim3(8, 32), blk, 0, stream>>>(attn_out, Wo_t, bo, src, resid1, nullptr, 4096, 1024, 1024, 1024);
  k_layernorm<1><<<dim3(4096), blk, 0, stream>>>(resid1, g1, be1, src2f, src2b);
  k_gemm<EPI_RELU_BF16><<<dim3(32, 32), blk, 0, stream>>>(src2b, W1_t, b1, nullptr, nullptr, ff1, 4096, 4096, 1024, 4096);
  k_gemm<EPI_ADD_F32><<<dim3(8, 32), blk, 0, stream>>>(ff1, W2_t, b2, src2f, resid2, nullptr, 4096, 1024, 4096, 1024);
  k_layernorm<0><<<dim3(4096), blk, 0, stream>>>(resid2, g2, be2, out, nullptr);
}

// Round 5
// 338.206 us; speedup vs baseline: 1.4161x; 1.0756x over previous
//
#include <hip/hip_runtime.h>
#include <math.h>

#define S_LEN 2048
#define DM 1024
#define NH 16
#define HD 64
#define DFF 4096
#define MROWS 4096  // S_LEN * 2 batch

typedef unsigned short u16;
typedef __attribute__((ext_vector_type(8))) __bf16 bf16x8;
typedef __attribute__((ext_vector_type(4))) float f32x4;
typedef __attribute__((ext_vector_type(16))) float f32x16;
typedef __attribute__((ext_vector_type(4))) int int32x4;

__device__ __forceinline__ u16 f2bf(float f) {
  unsigned u = __float_as_uint(f);
  unsigned r = (u + 0x7fffu + ((u >> 16) & 1u)) >> 16;  // RNE
  return (u16)r;
}

__device__ __forceinline__ float bf2f(u16 u) {
  return __uint_as_float((unsigned)u << 16);
}

__device__ __forceinline__ unsigned cvtpk_bf16(float lo, float hi) {
  unsigned r;
  asm("v_cvt_pk_bf16_f32 %0, %1, %2" : "=v"(r) : "v"(lo), "v"(hi));
  return r;
}

__device__ __forceinline__ void gload_lds16(const void* g, void* l) {
  __builtin_amdgcn_global_load_lds((__attribute__((address_space(1))) void*)g,
                                   (__attribute__((address_space(3))) void*)l, 16, 0, 0);
}

// ---------- transpose + fp32->bf16 weights: W (K x N) -> Wt (N x K) ----------
__global__ __launch_bounds__(256) void k_transpose_bf16(const float* __restrict__ W,
                                                        u16* __restrict__ Wt, int K, int N) {
  __shared__ float tile[32][33];
  int n0 = blockIdx.x * 32, k0 = blockIdx.y * 32;
  int tx = threadIdx.x & 31, ty = threadIdx.x >> 5;
  #pragma unroll
  for (int r = ty; r < 32; r += 8) tile[r][tx] = W[(size_t)(k0 + r) * N + n0 + tx];
  __syncthreads();
  #pragma unroll
  for (int r = ty; r < 32; r += 8) Wt[(size_t)(n0 + r) * K + k0 + tx] = f2bf(tile[tx][r]);
}

__global__ __launch_bounds__(256) void k_f2bf4(const float4* __restrict__ in,
                                               ushort4* __restrict__ out, int n4) {
  int i = blockIdx.x * 256 + threadIdx.x;
  if (i >= n4) return;
  float4 v = in[i];
  ushort4 o;
  o.x = f2bf(v.x); o.y = f2bf(v.y); o.z = f2bf(v.z); o.w = f2bf(v.w);
  out[i] = o;
}

__global__ __launch_bounds__(256) void k_rope_table(float* __restrict__ cosT,
                                                    float* __restrict__ sinT) {
  int idx = blockIdx.x * 256 + threadIdx.x;
  if (idx >= S_LEN * 32) return;
  int s = idx >> 5, i = idx & 31;
  float inv = powf(10000.f, -(float)(2 * i) / 64.f);
  float ang = (float)s * inv;
  cosT[idx] = cosf(ang);
  sinT[idx] = sinf(ang);
}

__global__ __launch_bounds__(256) void k_cat3(const float* __restrict__ a, const float* __restrict__ b,
                                              const float* __restrict__ c, float* __restrict__ o) {
  int i = blockIdx.x * 256 + threadIdx.x;
  if (i >= 3072) return;
  o[i] = i < 1024 ? a[i] : (i < 2048 ? b[i - 1024] : c[i - 2048]);
}

// ---------- mask tile flags: 0 = all pass (>=0.1), 1 = mixed/masked ----------
__global__ __launch_bounds__(256) void k_mask_flags(const float* __restrict__ mask,
                                                    unsigned char* __restrict__ flags) {
  int kt = blockIdx.x, qt = blockIdx.y;
  const float* mp = mask + (size_t)(qt * 64) * S_LEN + kt * 64;
  int tr = threadIdx.x >> 2;
  int tc = (threadIdx.x & 3) * 16;
  int ok = 1;
  #pragma unroll
  for (int c = 0; c < 16; c += 4) {
    float4 v = *(const float4*)(mp + (size_t)tr * S_LEN + tc + c);
    ok &= (v.x >= 0.1f) & (v.y >= 0.1f) & (v.z >= 0.1f) & (v.w >= 0.1f);
  }
  ok = __all(ok) ? 1 : 0;
  __shared__ int sh[4];
  if ((threadIdx.x & 63) == 0) sh[threadIdx.x >> 6] = ok;
  __syncthreads();
  if (threadIdx.x == 0) flags[qt * 32 + kt] = (sh[0] & sh[1] & sh[2] & sh[3]) ? 0 : 1;
}

// ---------- m97-structure bf16 GEMM with K-slicing (blockIdx.z) ----------
// EPI_F32: fp32 out + bias. EPI_RELU_BF16: bf16 relu out + bias.
// EPI_PARTF/EPI_PARTB: K-split partials (no bias), fp32/bf16, slice z at Cf/Cb + z*M*ldc.
enum { EPI_F32 = 0, EPI_RELU_BF16 = 2, EPI_PARTF = 3, EPI_PARTB = 4 };

template <int EPI>
__global__ __launch_bounds__(256) void k_gemm(const u16* __restrict__ A, const u16* __restrict__ Bt,
                                              const float* __restrict__ bias,
                                              float* __restrict__ Cf, u16* __restrict__ Cb,
                                              int M, int N, int K, int ldc, int Kc) {
  __shared__ __attribute__((aligned(16))) u16 As[128 * 32];
  __shared__ __attribute__((aligned(16))) u16 Bs[128 * 32];
  int m0 = blockIdx.y * 128, n0 = blockIdx.x * 128;
  int kz = blockIdx.z * Kc;
  int tid = threadIdx.x;
  int lane = tid & 63, w = tid >> 6;
  int wm = (w >> 1) * 64, wn = (w & 1) * 64;
  int l15 = lane & 15, l4 = lane >> 4;

  f32x4 acc[4][4] = {};

  for (int k0 = kz; k0 < kz + Kc; k0 += 32) {
    __syncthreads();
    #pragma unroll
    for (int i = 0; i < 2; ++i) {
      int sl = i * 256 + w * 64;
      int sg = sl + lane;
      const u16* ga = A + (size_t)(m0 + (sg >> 2)) * K + k0 + (sg & 3) * 8;
      gload_lds16(ga, &As[sl * 8]);
      const u16* gb = Bt + (size_t)(n0 + (sg >> 2)) * K + k0 + (sg & 3) * 8;
      gload_lds16(gb, &Bs[sl * 8]);
    }
    __syncthreads();

    bf16x8 af[4], bfr[4];
    #pragma unroll
    for (int i = 0; i < 4; ++i)
      af[i] = *(const bf16x8*)&As[(wm + i * 16 + l15) * 32 + l4 * 8];
    #pragma unroll
    for (int j = 0; j < 4; ++j)
      bfr[j] = *(const bf16x8*)&Bs[(wn + j * 16 + l15) * 32 + l4 * 8];
    #pragma unroll
    for (int i = 0; i < 4; ++i)
      #pragma unroll
      for (int j = 0; j < 4; ++j)
        acc[i][j] = __builtin_amdgcn_mfma_f32_16x16x32_bf16(af[i], bfr[j], acc[i][j], 0, 0, 0);
  }

  size_t zoff = (size_t)blockIdx.z * M * ldc;
  #pragma unroll
  for (int i = 0; i < 4; ++i) {
    #pragma unroll
    for (int j = 0; j < 4; ++j) {
      int col = n0 + wn + j * 16 + l15;
      float bv = (EPI == EPI_PARTF || EPI == EPI_PARTB) ? 0.f : bias[col];
      #pragma unroll
      for (int r = 0; r < 4; ++r) {
        int m = m0 + wm + i * 16 + l4 * 4 + r;
        float v = acc[i][j][r] + bv;
        size_t o = (size_t)m * ldc + col;
        if (EPI == EPI_F32) Cf[o] = v;
        else if (EPI == EPI_RELU_BF16) Cb[o] = f2bf(fmaxf(v, 0.f));
        else if (EPI == EPI_PARTF) Cf[zoff + o] = v;
        else Cb[zoff + o] = f2bf(v);
      }
    }
  }
}

// ---------- RoPE + head-split; Q pre-scaled by log2(e)/sqrt(HD) (exp2 domain) ----------
#define QSCALE 0.180336881f
__global__ __launch_bounds__(256) void k_rope_heads(const float* __restrict__ QKV,
                                                    const float* __restrict__ cosT,
                                                    const float* __restrict__ sinT,
                                                    u16* __restrict__ Qh, u16* __restrict__ Kh,
                                                    u16* __restrict__ Vt) {
  int idx = blockIdx.x * 256 + threadIdx.x;
  if (idx >= MROWS * 512) return;
  int m = idx >> 9, c2 = idx & 511;
  int h = c2 >> 5, i = c2 & 31, d = 2 * i;
  int s = m >> 1, b = m & 1;
  int bh = b * NH + h;
  size_t base = (size_t)m * 3072 + h * 64 + d;
  float q0 = QKV[base], q1 = QKV[base + 1];
  float k0 = QKV[base + 1024], k1 = QKV[base + 1025];
  float v0 = QKV[base + 2048], v1 = QKV[base + 2049];
  float c = cosT[s * 32 + i], sn = sinT[s * 32 + i];
  size_t ho = ((size_t)bh * S_LEN + s) * 64 + d;
  Qh[ho]     = f2bf((q0 * c - q1 * sn) * QSCALE);
  Qh[ho + 1] = f2bf((q1 * c + q0 * sn) * QSCALE);
  Kh[ho]     = f2bf(k0 * c - k1 * sn);
  Kh[ho + 1] = f2bf(k1 * c + k0 * sn);
  size_t vo = ((size_t)bh * 64 + d) * S_LEN + s;
  Vt[vo] = f2bf(v0);
  Vt[vo + S_LEN] = f2bf(v1);
}

// ---------- flash attention: swapped-QK^T 32x32x16, in-register softmax ----------
__global__ __launch_bounds__(256) void k_attn(const u16* __restrict__ Qh, const u16* __restrict__ Kh,
                                              const u16* __restrict__ Vt,
                                              const float* __restrict__ mask,
                                              const unsigned char* __restrict__ flags,
                                              u16* __restrict__ Out) {
  __shared__ __attribute__((aligned(16))) u16 Ks[128 * 64];
  __shared__ __attribute__((aligned(16))) u16 Vs[64 * 128];
  int bh = blockIdx.y;
  int q0 = blockIdx.x * 128;
  int b = bh >> 4, h = bh & 15;
  int tid = threadIdx.x, lane = tid & 63, w = tid >> 6;
  int l31 = lane & 31, l5 = lane >> 5;

  int qrow = q0 + w * 32 + l31;
  int qt = qrow >> 6;  // wave-uniform

  bf16x8 qf[4];
  {
    const u16* qp = Qh + ((size_t)bh * S_LEN + qrow) * 64 + l5 * 8;
    #pragma unroll
    for (int dc = 0; dc < 4; ++dc) qf[dc] = *(const bf16x8*)(qp + dc * 16);
  }

  float m_run = -1e30f, l_run = 0.f;
  f32x16 oA = {}, oB = {};

  for (int kv0 = 0; kv0 < S_LEN; kv0 += 128) {
    __syncthreads();
    #pragma unroll
    for (int i = 0; i < 4; ++i) {
      int sid = i * 256 + tid;
      int kr = sid >> 3, kslot = sid & 7;
      gload_lds16(Kh + ((size_t)bh * S_LEN + kv0 + kr) * 64 + (kslot ^ (kr & 7)) * 8, &Ks[sid * 8]);
      int vr = sid >> 4, vslot = sid & 15;
      gload_lds16(Vt + ((size_t)bh * 64 + vr) * S_LEN + kv0 + ((vslot ^ (vr & 15))) * 8, &Vs[sid * 8]);
    }
    __syncthreads();

    #pragma unroll
    for (int ksub = 0; ksub < 2; ++ksub) {
      int koff = ksub * 64;
      f32x16 sA = {}, sB = {};
      #pragma unroll
      for (int dc = 0; dc < 4; ++dc) {
        int r0 = koff + l31;
        int r1 = koff + 32 + l31;
        int slot = (dc * 2 + l5) ^ (l31 & 7);
        bf16x8 ka0 = *(const bf16x8*)&Ks[r0 * 64 + slot * 8];
        bf16x8 ka1 = *(const bf16x8*)&Ks[r1 * 64 + slot * 8];
        sA = __builtin_amdgcn_mfma_f32_32x32x16_bf16(ka0, qf[dc], sA, 0, 0, 0);
        sB = __builtin_amdgcn_mfma_f32_32x32x16_bf16(ka1, qf[dc], sB, 0, 0, 0);
      }

      int fl = flags[qt * 32 + ((kv0 + koff) >> 6)];
      if (fl) {
        const float* mrow = mask + (size_t)qrow * S_LEN + kv0 + koff;
        #pragma unroll
        for (int r = 0; r < 16; ++r) {
          int key = (r & 3) + 8 * (r >> 2) + 4 * l5;
          if (mrow[key] < 0.1f) sA[r] = -1e30f;
          if (mrow[key + 32] < 0.1f) sB[r] = -1e30f;
        }
      }

      float pm = m_run;
      #pragma unroll
      for (int r = 0; r < 16; ++r) pm = fmaxf(pm, fmaxf(sA[r], sB[r]));
      pm = fmaxf(pm, __shfl_xor(pm, 32, 64));
      if (!__all(pm <= m_run + 8.f)) {  // defer-max (log2 units)
        float corr = __builtin_amdgcn_exp2f(m_run - pm);
        m_run = pm;
        l_run *= corr;
        #pragma unroll
        for (int r = 0; r < 16; ++r) { oA[r] *= corr; oB[r] *= corr; }
      }
      float ps = 0.f;
      #pragma unroll
      for (int r = 0; r < 16; ++r) {
        sA[r] = __builtin_amdgcn_exp2f(sA[r] - m_run);
        sB[r] = __builtin_amdgcn_exp2f(sB[r] - m_run);
        ps += sA[r] + sB[r];
      }
      l_run += ps;

      #pragma unroll
      for (int kh = 0; kh < 2; ++kh) {
        f32x16 s = kh ? sB : sA;
        #pragma unroll
        for (int c = 0; c < 2; ++c) {
          int base = c * 8;
          unsigned u0 = cvtpk_bf16(s[base + 0], s[base + 1]);
          unsigned u1 = cvtpk_bf16(s[base + 2], s[base + 3]);
          unsigned u2 = cvtpk_bf16(s[base + 4], s[base + 5]);
          unsigned u3 = cvtpk_bf16(s[base + 6], s[base + 7]);
          asm volatile("v_permlane32_swap_b32 %0, %1" : "+v"(u0), "+v"(u2));
          asm volatile("v_permlane32_swap_b32 %0, %1" : "+v"(u1), "+v"(u3));
          int32x4 wds = {(int)u0, (int)u1, (int)u2, (int)u3};
          bf16x8 pb = *(bf16x8*)&wds;
          int kslot = ksub * 8 + (kh * 2 + c) * 2 + l5;
          int vr0 = l31, vr1 = 32 + l31;
          bf16x8 va0 = *(const bf16x8*)&Vs[vr0 * 128 + (kslot ^ (vr0 & 15)) * 8];
          bf16x8 va1 = *(const bf16x8*)&Vs[vr1 * 128 + (kslot ^ (vr1 & 15)) * 8];
          oA = __builtin_amdgcn_mfma_f32_32x32x16_bf16(va0, pb, oA, 0, 0, 0);
          oB = __builtin_amdgcn_mfma_f32_32x32x16_bf16(va1, pb, oB, 0, 0, 0);
        }
      }
    }
  }

  float l_tot = l_run + __shfl_xor(l_run, 32, 64);
  float inv = 1.f / l_tot;
  int mrow = qrow * 2 + b;
  u16* op = Out + (size_t)mrow * DM + h * 64;
  #pragma unroll
  for (int db = 0; db < 2; ++db) {
    f32x16 o = db ? oB : oA;
    #pragma unroll
    for (int g = 0; g < 4; ++g) {
      int d0 = db * 32 + 8 * g + 4 * l5;
      ushort4 st;
      st.x = f2bf(o[4 * g + 0] * inv);
      st.y = f2bf(o[4 * g + 1] * inv);
      st.z = f2bf(o[4 * g + 2] * inv);
      st.w = f2bf(o[4 * g + 3] * inv);
      *(ushort4*)(op + d0) = st;
    }
  }
}

// ---------- fused LayerNorms ----------
__device__ __forceinline__ float wave_sum(float v) {
  #pragma unroll
  for (int off = 32; off >= 1; off >>= 1) v += __shfl_xor(v, off, 64);
  return v;
}

// LN1: x = src + (woP0 + woP1 + bo); y = LN(x)*g1+be1 -> src2f (fp32) + src2b (bf16)
__global__ __launch_bounds__(256) void k_ln1(const float* __restrict__ p0, const float* __restrict__ p1,
                                             const float* __restrict__ src, const float* __restrict__ bo,
                                             const float* __restrict__ gw, const float* __restrict__ bw,
                                             float* __restrict__ Yf, u16* __restrict__ Yb) {
  int m = blockIdx.x;
  int tid = threadIdx.x, lane = tid & 63, w = tid >> 6;
  __shared__ float part[4];
  __shared__ float shv[2];
  float4 a = ((const float4*)(p0 + (size_t)m * DM))[tid];
  float4 bb = ((const float4*)(p1 + (size_t)m * DM))[tid];
  float4 sc = ((const float4*)(src + (size_t)m * DM))[tid];
  float4 bv = ((const float4*)bo)[tid];
  float4 v = make_float4(a.x + bb.x + sc.x + bv.x, a.y + bb.y + sc.y + bv.y,
                         a.z + bb.z + sc.z + bv.z, a.w + bb.w + sc.w + bv.w);
  float s = wave_sum(v.x + v.y + v.z + v.w);
  if (lane == 0) part[w] = s;
  __syncthreads();
  if (tid == 0) shv[0] = (part[0] + part[1] + part[2] + part[3]) * (1.f / DM);
  __syncthreads();
  float mu = shv[0];
  float d0 = v.x - mu, d1 = v.y - mu, d2 = v.z - mu, d3 = v.w - mu;
  float q = wave_sum(d0 * d0 + d1 * d1 + d2 * d2 + d3 * d3);
  if (lane == 0) part[w] = q;
  __syncthreads();
  if (tid == 0) shv[1] = rsqrtf((part[0] + part[1] + part[2] + part[3]) * (1.f / DM) + 1e-5f);
  __syncthreads();
  float rstd = shv[1];
  float4 g4 = ((const float4*)gw)[tid];
  float4 b4 = ((const float4*)bw)[tid];
  float y0 = d0 * rstd * g4.x + b4.x;
  float y1 = d1 * rstd * g4.y + b4.y;
  float y2 = d2 * rstd * g4.z + b4.z;
  float y3 = d3 * rstd * g4.w + b4.w;
  ((float4*)(Yf + (size_t)m * DM))[tid] = make_float4(y0, y1, y2, y3);
  ushort4 o;
  o.x = f2bf(y0); o.y = f2bf(y1); o.z = f2bf(y2); o.w = f2bf(y3);
  ((ushort4*)(Yb + (size_t)m * DM))[tid] = o;
}

// LN2: x = src2 + (sum_z ffP[z] + b2); out = LN(x)*g2+be2 (fp32)
__global__ __launch_bounds__(256) void k_ln2(const u16* __restrict__ pb, const float* __restrict__ src2,
                                             const float* __restrict__ b2,
                                             const float* __restrict__ gw, const float* __restrict__ bw,
                                             float* __restrict__ out) {
  int m = blockIdx.x;
  int tid = threadIdx.x, lane = tid & 63, w = tid >> 6;
  __shared__ float part[4];
  __shared__ float shv[2];
  float4 sc = ((const float4*)(src2 + (size_t)m * DM))[tid];
  float4 bv = ((const float4*)b2)[tid];
  float vx = sc.x + bv.x, vy = sc.y + bv.y, vz = sc.z + bv.z, vw = sc.w + bv.w;
  #pragma unroll
  for (int z = 0; z < 4; ++z) {
    ushort4 qv = ((const ushort4*)(pb + (size_t)z * MROWS * DM + (size_t)m * DM))[tid];
    vx += bf2f(qv.x); vy += bf2f(qv.y); vz += bf2f(qv.z); vw += bf2f(qv.w);
  }
  float s = wave_sum(vx + vy + vz + vw);
  if (lane == 0) part[w] = s;
  __syncthreads();
  if (tid == 0) shv[0] = (part[0] + part[1] + part[2] + part[3]) * (1.f / DM);
  __syncthreads();
  float mu = shv[0];
  float d0 = vx - mu, d1 = vy - mu, d2 = vz - mu, d3 = vw - mu;
  float q = wave_sum(d0 * d0 + d1 * d1 + d2 * d2 + d3 * d3);
  if (lane == 0) part[w] = q;
  __syncthreads();
  if (tid == 0) shv[1] = rsqrtf((part[0] + part[1] + part[2] + part[3]) * (1.f / DM) + 1e-5f);
  __syncthreads();
  float rstd = shv[1];
  float4 g4 = ((const float4*)gw)[tid];
  float4 b4 = ((const float4*)bw)[tid];
  ((float4*)(out + (size_t)m * DM))[tid] =
      make_float4(d0 * rstd * g4.x + b4.x, d1 * rstd * g4.y + b4.y,
                  d2 * rstd * g4.z + b4.z, d3 * rstd * g4.w + b4.w);
}

extern "C" void kernel_launch(void* const* d_in, const int* in_sizes, int n_in,
                              void* d_out, int out_size, void* d_ws, size_t ws_size,
                              hipStream_t stream) {
  (void)in_sizes; (void)n_in; (void)out_size; (void)ws_size;
  const float* src  = (const float*)d_in[0];
  const float* mask = (const float*)d_in[1];
  const float* Wq = (const float*)d_in[2];  const float* bq  = (const float*)d_in[3];
  const float* Wk = (const float*)d_in[4];  const float* bk  = (const float*)d_in[5];
  const float* Wv = (const float*)d_in[6];  const float* bv  = (const float*)d_in[7];
  const float* Wo = (const float*)d_in[8];  const float* bo  = (const float*)d_in[9];
  const float* W1 = (const float*)d_in[10]; const float* b1  = (const float*)d_in[11];
  const float* W2 = (const float*)d_in[12]; const float* b2  = (const float*)d_in[13];
  const float* g1 = (const float*)d_in[14]; const float* be1 = (const float*)d_in[15];
  const float* g2 = (const float*)d_in[16]; const float* be2 = (const float*)d_in[17];
  float* out = (float*)d_out;

  char* base = (char*)d_ws;
  size_t off = 0;
  auto carve = [&](size_t bytes) -> void* {
    void* r = base + off;
    off += (bytes + 255) & ~(size_t)255;
    return r;
  };
  u16* Wq_t = (u16*)carve(2ull * 1024 * 1024);  // Wq_t/Wk_t/Wv_t contiguous -> fused N=3072 GEMM
  u16* Wk_t = (u16*)carve(2ull * 1024 * 1024);
  u16* Wv_t = (u16*)carve(2ull * 1024 * 1024);
  u16* Wo_t = (u16*)carve(2ull * 1024 * 1024);
  u16* W1_t = (u16*)carve(2ull * 4096 * 1024);
  u16* W2_t = (u16*)carve(2ull * 1024 * 4096);
  u16* Xbf  = (u16*)carve(2ull * 4096 * 1024);
  float* cosT = (float*)carve(4ull * 2048 * 32);
  float* sinT = (float*)carve(4ull * 2048 * 32);
  float* bqkv = (float*)carve(4ull * 3072);
  unsigned char* mflags = (unsigned char*)carve(1024);
  u16* attn_out = (u16*)carve(2ull * 4096 * 1024);
  float* src2f = (float*)carve(4ull * 4096 * 1024);     // dedicated: live LN1 -> LN2
  float* QKV = (float*)carve(4ull * 4096 * 3072);       // 48MB, multiply reused (see below)
  u16* Qh = (u16*)carve(2ull * 32 * 2048 * 64);         // 8MB
  u16* Kh = (u16*)carve(2ull * 32 * 2048 * 64);         // 8MB (contiguous after Qh)
  u16* Vt = (u16*)carve(2ull * 32 * 2048 * 64);         // 8MB
  // Aliases (lifetimes):
  //   QKV fp32 (48MB): dead after rope_heads.
  //     woP0 = QKV+0 (16MB fp32), woP1 = QKV+16MB  : Wo split-K partials, consumed by LN1.
  //     ff1  = QKV+0 (32MB bf16)                   : written after LN1 (woP dead).
  //     ffPb = QKV+32MB .. +64MB (4 x 8MB bf16)    : FF2 partials; spans QKV tail + Qh + Kh
  //                                                  (Qh/Kh dead after attn). Consumed by LN2.
  //   src2b = Vt (8MB bf16): Vt dead after attn; consumed by FF1.
  float* woP0 = QKV;
  float* woP1 = QKV + 4ull * 1024 * 1024;
  u16* ff1 = (u16*)QKV;
  u16* ffPb = (u16*)((char*)QKV + 32ull * 1024 * 1024);
  u16* src2b = (u16*)Vt;

  dim3 blk(256);
  k_transpose_bf16<<<dim3(32, 32), blk, 0, stream>>>(Wq, Wq_t, 1024, 1024);
  k_transpose_bf16<<<dim3(32, 32), blk, 0, stream>>>(Wk, Wk_t, 1024, 1024);
  k_transpose_bf16<<<dim3(32, 32), blk, 0, stream>>>(Wv, Wv_t, 1024, 1024);
  k_transpose_bf16<<<dim3(32, 32), blk, 0, stream>>>(Wo, Wo_t, 1024, 1024);
  k_transpose_bf16<<<dim3(128, 32), blk, 0, stream>>>(W1, W1_t, 1024, 4096);
  k_transpose_bf16<<<dim3(32, 128), blk, 0, stream>>>(W2, W2_t, 4096, 1024);
  k_f2bf4<<<dim3(4096), blk, 0, stream>>>((const float4*)src, (ushort4*)Xbf, 4096 * 1024 / 4);
  k_rope_table<<<dim3(256), blk, 0, stream>>>(cosT, sinT);
  k_cat3<<<dim3(12), blk, 0, stream>>>(bq, bk, bv, bqkv);
  k_mask_flags<<<dim3(32, 32), blk, 0, stream>>>(mask, mflags);
  // fused QKV projection (N=3072), 768 blocks = 3/CU
  k_gemm<EPI_F32><<<dim3(24, 32, 1), blk, 0, stream>>>(Xbf, Wq_t, bqkv, QKV, nullptr, 4096, 3072, 1024, 3072, 1024);
  k_rope_heads<<<dim3(MROWS * 512 / 256), blk, 0, stream>>>(QKV, cosT, sinT, Qh, Kh, Vt);
  k_attn<<<dim3(16, 32), blk, 0, stream>>>(Qh, Kh, Vt, mask, mflags, attn_out);
  // O-projection, split-K=2 (512 blocks = 2/CU), fp32 partials; reduce fused in LN1
  k_gemm<EPI_PARTF><<<dim3(8, 32, 2), blk, 0, stream>>>(attn_out, Wo_t, nullptr, woP0, nullptr, 4096, 1024, 1024, 1024, 512);
  k_ln1<<<dim3(4096), blk, 0, stream>>>(woP0, woP1, src, bo, g1, be1, src2f, src2b);
  // FF1 with ReLU (bf16 out), 1024 blocks = 4/CU
  k_gemm<EPI_RELU_BF16><<<dim3(32, 32, 1), blk, 0, stream>>>(src2b, W1_t, b1, nullptr, ff1, 4096, 4096, 1024, 4096, 1024);
  // FF2, split-K=4 (1024 blocks = 4/CU), bf16 partials; reduce fused in LN2
  k_gemm<EPI_PARTB><<<dim3(8, 32, 4), blk, 0, stream>>>(ff1, W2_t, nullptr, nullptr, ffPb, 4096, 1024, 4096, 1024, 1024);
  k_ln2<<<dim3(4096), blk, 0, stream>>>(ffPb, src2f, b2, g2, be2, out);
}

// Round 6
// 316.368 us; speedup vs baseline: 1.5138x; 1.0690x over previous
//
#include <hip/hip_runtime.h>
#include <math.h>

#define S_LEN 2048
#define DM 1024
#define NH 16
#define HD 64
#define DFF 4096
#define MROWS 4096  // S_LEN * 2 batch

typedef unsigned short u16;
typedef __attribute__((ext_vector_type(8))) __bf16 bf16x8;
typedef __attribute__((ext_vector_type(4))) float f32x4;
typedef __attribute__((ext_vector_type(16))) float f32x16;
typedef __attribute__((ext_vector_type(4))) int int32x4;

__device__ __forceinline__ u16 f2bf(float f) {
  unsigned u = __float_as_uint(f);
  unsigned r = (u + 0x7fffu + ((u >> 16) & 1u)) >> 16;  // RNE
  return (u16)r;
}

__device__ __forceinline__ float bf2f(u16 u) {
  return __uint_as_float((unsigned)u << 16);
}

__device__ __forceinline__ unsigned cvtpk_bf16(float lo, float hi) {
  unsigned r;
  asm("v_cvt_pk_bf16_f32 %0, %1, %2" : "=v"(r) : "v"(lo), "v"(hi));
  return r;
}

__device__ __forceinline__ void gload_lds16(const void* g, void* l) {
  __builtin_amdgcn_global_load_lds((__attribute__((address_space(1))) void*)g,
                                   (__attribute__((address_space(3))) void*)l, 16, 0, 0);
}

// ---------- transpose + fp32->bf16 weights: W (K x N) -> Wt (N x K) ----------
__global__ __launch_bounds__(256) void k_transpose_bf16(const float* __restrict__ W,
                                                        u16* __restrict__ Wt, int K, int N) {
  __shared__ float tile[32][33];
  int n0 = blockIdx.x * 32, k0 = blockIdx.y * 32;
  int tx = threadIdx.x & 31, ty = threadIdx.x >> 5;
  #pragma unroll
  for (int r = ty; r < 32; r += 8) tile[r][tx] = W[(size_t)(k0 + r) * N + n0 + tx];
  __syncthreads();
  #pragma unroll
  for (int r = ty; r < 32; r += 8) Wt[(size_t)(n0 + r) * K + k0 + tx] = f2bf(tile[tx][r]);
}

__global__ __launch_bounds__(256) void k_f2bf4(const float4* __restrict__ in,
                                               ushort4* __restrict__ out, int n4) {
  int i = blockIdx.x * 256 + threadIdx.x;
  if (i >= n4) return;
  float4 v = in[i];
  ushort4 o;
  o.x = f2bf(v.x); o.y = f2bf(v.y); o.z = f2bf(v.z); o.w = f2bf(v.w);
  out[i] = o;
}

__global__ __launch_bounds__(256) void k_rope_table(float* __restrict__ cosT,
                                                    float* __restrict__ sinT) {
  int idx = blockIdx.x * 256 + threadIdx.x;
  if (idx >= S_LEN * 32) return;
  int s = idx >> 5, i = idx & 31;
  float inv = powf(10000.f, -(float)(2 * i) / 64.f);
  float ang = (float)s * inv;
  cosT[idx] = cosf(ang);
  sinT[idx] = sinf(ang);
}

__global__ __launch_bounds__(256) void k_cat3(const float* __restrict__ a, const float* __restrict__ b,
                                              const float* __restrict__ c, float* __restrict__ o) {
  int i = blockIdx.x * 256 + threadIdx.x;
  if (i >= 3072) return;
  o[i] = i < 1024 ? a[i] : (i < 2048 ? b[i - 1024] : c[i - 2048]);
}

// ---------- mask tile flags: 0 = all pass (>=0.1), 1 = mixed/masked ----------
__global__ __launch_bounds__(256) void k_mask_flags(const float* __restrict__ mask,
                                                    unsigned char* __restrict__ flags) {
  int kt = blockIdx.x, qt = blockIdx.y;
  const float* mp = mask + (size_t)(qt * 64) * S_LEN + kt * 64;
  int tr = threadIdx.x >> 2;
  int tc = (threadIdx.x & 3) * 16;
  int ok = 1;
  #pragma unroll
  for (int c = 0; c < 16; c += 4) {
    float4 v = *(const float4*)(mp + (size_t)tr * S_LEN + tc + c);
    ok &= (v.x >= 0.1f) & (v.y >= 0.1f) & (v.z >= 0.1f) & (v.w >= 0.1f);
  }
  ok = __all(ok) ? 1 : 0;
  __shared__ int sh[4];
  if ((threadIdx.x & 63) == 0) sh[threadIdx.x >> 6] = ok;
  __syncthreads();
  if (threadIdx.x == 0) flags[qt * 32 + kt] = (sh[0] & sh[1] & sh[2] & sh[3]) ? 0 : 1;
}

// ---------- 256x256-tile pipelined bf16 GEMM ----------
// 8 waves (2M x 4N), BK=32, 4 LDS K-tile buffers, prefetch distance 3,
// counted vmcnt + raw s_barrier (no drain), setprio around MFMA cluster,
// slot^(row&3) LDS swizzle (pre-swizzled global source, linear DMA dest),
// bijective XCD-aware block swizzle. C = A(MxK) @ Bt(NxK)^T [+ bias/epilogue].
enum { EPI_F32 = 0, EPI_RELU_BF16 = 2, EPI_PARTB = 4 };

template <int EPI>
__global__ __launch_bounds__(512, 2) void k_gemm256(const u16* __restrict__ A,
                                                    const u16* __restrict__ Bt,
                                                    const float* __restrict__ bias,
                                                    float* __restrict__ Cf, u16* __restrict__ Cb,
                                                    int M, int N, int K, int ldc, int Kc) {
  __shared__ __attribute__((aligned(16))) u16 As[4][256 * 32];
  __shared__ __attribute__((aligned(16))) u16 Bs[4][256 * 32];

  // XCD-aware bijective block swizzle (nwg % 8 == 0 for all our grids)
  int nx = gridDim.x;
  int nwg = nx * gridDim.y;
  int flat = blockIdx.y * nx + blockIdx.x;
  int id = (flat & 7) * (nwg >> 3) + (flat >> 3);
  int n0 = (id % nx) * 256;
  int m0 = (id / nx) * 256;
  int kz = blockIdx.z * Kc;

  int tid = threadIdx.x;
  int lane = tid & 63, w = tid >> 6;
  int wm = (w >> 2) * 128, wn = (w & 3) * 64;
  int l15 = lane & 15, l4 = lane >> 4;
  int NT = Kc >> 5;  // K-tiles of 32 (all call sites: NT >= 8, NT % 2 == 0)

  // per-thread staging source pointers (advance 32 elems per K-tile)
  const u16* aS[2];
  const u16* bS[2];
  int dslot[2];
  #pragma unroll
  for (int j = 0; j < 2; ++j) {
    int P = j * 512 + tid;          // physical 16B slot in 1024-slot buffer
    int r = P >> 2;                  // row 0..255
    int sl = (P & 3) ^ (r & 3);      // logical slot (involution swizzle)
    aS[j] = A + (size_t)(m0 + r) * K + kz + sl * 8;
    bS[j] = Bt + (size_t)(n0 + r) * K + kz + sl * 8;
    dslot[j] = j * 512 + w * 64;     // wave-uniform DMA dest slot base
  }

  f32x4 acc[8][4] = {};

  // prologue: stage K-tiles 0,1,2
  #pragma unroll
  for (int t = 0; t < 3; ++t) {
    #pragma unroll
    for (int j = 0; j < 2; ++j) {
      gload_lds16(aS[j] + t * 32, &As[t][dslot[j] * 8]);
      gload_lds16(bS[j] + t * 32, &Bs[t][dslot[j] * 8]);
    }
  }

  for (int t = 0; t < NT; ++t) {
    int buf = t & 3;
    // counted wait: tiles issued beyond t = min(t+2, NT-1) - t  ->  4 loads each
    if (t < NT - 2) asm volatile("s_waitcnt vmcnt(8)" ::: "memory");
    else if (t == NT - 2) asm volatile("s_waitcnt vmcnt(4)" ::: "memory");
    else asm volatile("s_waitcnt vmcnt(0)" ::: "memory");
    __builtin_amdgcn_s_barrier();  // raw: does NOT drain counters

    if (t + 3 < NT) {  // stage tile t+3 into buf[(t+3)&3] (its readers are behind this barrier)
      int tn = t + 3;
      int bn = tn & 3;
      #pragma unroll
      for (int j = 0; j < 2; ++j) {
        gload_lds16(aS[j] + tn * 32, &As[bn][dslot[j] * 8]);
        gload_lds16(bS[j] + tn * 32, &Bs[bn][dslot[j] * 8]);
      }
    }

    bf16x8 af[8], bq[4];
    #pragma unroll
    for (int m = 0; m < 8; ++m) {
      int r = wm + m * 16 + l15;
      af[m] = *(const bf16x8*)&As[buf][r * 32 + (l4 ^ (r & 3)) * 8];
    }
    #pragma unroll
    for (int n = 0; n < 4; ++n) {
      int r = wn + n * 16 + l15;
      bq[n] = *(const bf16x8*)&Bs[buf][r * 32 + (l4 ^ (r & 3)) * 8];
    }
    __builtin_amdgcn_s_setprio(1);
    #pragma unroll
    for (int m = 0; m < 8; ++m)
      #pragma unroll
      for (int n = 0; n < 4; ++n)
        acc[m][n] = __builtin_amdgcn_mfma_f32_16x16x32_bf16(af[m], bq[n], acc[m][n], 0, 0, 0);
    __builtin_amdgcn_s_setprio(0);
  }

  size_t zoff = (size_t)blockIdx.z * M * ldc;
  #pragma unroll
  for (int m = 0; m < 8; ++m) {
    #pragma unroll
    for (int n = 0; n < 4; ++n) {
      int col = n0 + wn + n * 16 + l15;
      float bv = (EPI == EPI_PARTB) ? 0.f : bias[col];
      #pragma unroll
      for (int r = 0; r < 4; ++r) {
        int row = m0 + wm + m * 16 + l4 * 4 + r;  // C/D: col=lane&15, row=(lane>>4)*4+reg
        float v = acc[m][n][r] + bv;
        size_t o = (size_t)row * ldc + col;
        if (EPI == EPI_F32) Cf[o] = v;
        else if (EPI == EPI_RELU_BF16) Cb[o] = f2bf(fmaxf(v, 0.f));
        else Cb[zoff + o] = f2bf(v);
      }
    }
  }
}

// ---------- RoPE + head-split; Q pre-scaled by log2(e)/sqrt(HD) (exp2 domain) ----------
#define QSCALE 0.180336881f
__global__ __launch_bounds__(256) void k_rope_heads(const float* __restrict__ QKV,
                                                    const float* __restrict__ cosT,
                                                    const float* __restrict__ sinT,
                                                    u16* __restrict__ Qh, u16* __restrict__ Kh,
                                                    u16* __restrict__ Vt) {
  int idx = blockIdx.x * 256 + threadIdx.x;
  if (idx >= MROWS * 512) return;
  int m = idx >> 9, c2 = idx & 511;
  int h = c2 >> 5, i = c2 & 31, d = 2 * i;
  int s = m >> 1, b = m & 1;
  int bh = b * NH + h;
  size_t base = (size_t)m * 3072 + h * 64 + d;
  float q0 = QKV[base], q1 = QKV[base + 1];
  float k0 = QKV[base + 1024], k1 = QKV[base + 1025];
  float v0 = QKV[base + 2048], v1 = QKV[base + 2049];
  float c = cosT[s * 32 + i], sn = sinT[s * 32 + i];
  size_t ho = ((size_t)bh * S_LEN + s) * 64 + d;
  Qh[ho]     = f2bf((q0 * c - q1 * sn) * QSCALE);
  Qh[ho + 1] = f2bf((q1 * c + q0 * sn) * QSCALE);
  Kh[ho]     = f2bf(k0 * c - k1 * sn);
  Kh[ho + 1] = f2bf(k1 * c + k0 * sn);
  size_t vo = ((size_t)bh * 64 + d) * S_LEN + s;
  Vt[vo] = f2bf(v0);
  Vt[vo + S_LEN] = f2bf(v1);
}

// ---------- flash attention: swapped-QK^T 32x32x16, in-register softmax ----------
__global__ __launch_bounds__(256) void k_attn(const u16* __restrict__ Qh, const u16* __restrict__ Kh,
                                              const u16* __restrict__ Vt,
                                              const float* __restrict__ mask,
                                              const unsigned char* __restrict__ flags,
                                              u16* __restrict__ Out) {
  __shared__ __attribute__((aligned(16))) u16 Ks[128 * 64];
  __shared__ __attribute__((aligned(16))) u16 Vs[64 * 128];
  int bh = blockIdx.y;
  int q0 = blockIdx.x * 128;
  int b = bh >> 4, h = bh & 15;
  int tid = threadIdx.x, lane = tid & 63, w = tid >> 6;
  int l31 = lane & 31, l5 = lane >> 5;

  int qrow = q0 + w * 32 + l31;
  int qt = qrow >> 6;  // wave-uniform

  bf16x8 qf[4];
  {
    const u16* qp = Qh + ((size_t)bh * S_LEN + qrow) * 64 + l5 * 8;
    #pragma unroll
    for (int dc = 0; dc < 4; ++dc) qf[dc] = *(const bf16x8*)(qp + dc * 16);
  }

  float m_run = -1e30f, l_run = 0.f;
  f32x16 oA = {}, oB = {};

  for (int kv0 = 0; kv0 < S_LEN; kv0 += 128) {
    __syncthreads();
    #pragma unroll
    for (int i = 0; i < 4; ++i) {
      int sid = i * 256 + tid;
      int kr = sid >> 3, kslot = sid & 7;
      gload_lds16(Kh + ((size_t)bh * S_LEN + kv0 + kr) * 64 + (kslot ^ (kr & 7)) * 8, &Ks[sid * 8]);
      int vr = sid >> 4, vslot = sid & 15;
      gload_lds16(Vt + ((size_t)bh * 64 + vr) * S_LEN + kv0 + ((vslot ^ (vr & 15))) * 8, &Vs[sid * 8]);
    }
    __syncthreads();

    #pragma unroll
    for (int ksub = 0; ksub < 2; ++ksub) {
      int koff = ksub * 64;
      f32x16 sA = {}, sB = {};
      #pragma unroll
      for (int dc = 0; dc < 4; ++dc) {
        int r0 = koff + l31;
        int r1 = koff + 32 + l31;
        int slot = (dc * 2 + l5) ^ (l31 & 7);
        bf16x8 ka0 = *(const bf16x8*)&Ks[r0 * 64 + slot * 8];
        bf16x8 ka1 = *(const bf16x8*)&Ks[r1 * 64 + slot * 8];
        sA = __builtin_amdgcn_mfma_f32_32x32x16_bf16(ka0, qf[dc], sA, 0, 0, 0);
        sB = __builtin_amdgcn_mfma_f32_32x32x16_bf16(ka1, qf[dc], sB, 0, 0, 0);
      }

      int fl = flags[qt * 32 + ((kv0 + koff) >> 6)];
      if (fl) {
        const float* mrow = mask + (size_t)qrow * S_LEN + kv0 + koff;
        #pragma unroll
        for (int r = 0; r < 16; ++r) {
          int key = (r & 3) + 8 * (r >> 2) + 4 * l5;
          if (mrow[key] < 0.1f) sA[r] = -1e30f;
          if (mrow[key + 32] < 0.1f) sB[r] = -1e30f;
        }
      }

      float pm = m_run;
      #pragma unroll
      for (int r = 0; r < 16; ++r) pm = fmaxf(pm, fmaxf(sA[r], sB[r]));
      pm = fmaxf(pm, __shfl_xor(pm, 32, 64));
      if (!__all(pm <= m_run + 8.f)) {  // defer-max (log2 units)
        float corr = __builtin_amdgcn_exp2f(m_run - pm);
        m_run = pm;
        l_run *= corr;
        #pragma unroll
        for (int r = 0; r < 16; ++r) { oA[r] *= corr; oB[r] *= corr; }
      }
      float ps = 0.f;
      #pragma unroll
      for (int r = 0; r < 16; ++r) {
        sA[r] = __builtin_amdgcn_exp2f(sA[r] - m_run);
        sB[r] = __builtin_amdgcn_exp2f(sB[r] - m_run);
        ps += sA[r] + sB[r];
      }
      l_run += ps;

      #pragma unroll
      for (int kh = 0; kh < 2; ++kh) {
        f32x16 s = kh ? sB : sA;
        #pragma unroll
        for (int c = 0; c < 2; ++c) {
          int base = c * 8;
          unsigned u0 = cvtpk_bf16(s[base + 0], s[base + 1]);
          unsigned u1 = cvtpk_bf16(s[base + 2], s[base + 3]);
          unsigned u2 = cvtpk_bf16(s[base + 4], s[base + 5]);
          unsigned u3 = cvtpk_bf16(s[base + 6], s[base + 7]);
          asm volatile("v_permlane32_swap_b32 %0, %1" : "+v"(u0), "+v"(u2));
          asm volatile("v_permlane32_swap_b32 %0, %1" : "+v"(u1), "+v"(u3));
          int32x4 wds = {(int)u0, (int)u1, (int)u2, (int)u3};
          bf16x8 pb = *(bf16x8*)&wds;
          int kslot = ksub * 8 + (kh * 2 + c) * 2 + l5;
          int vr0 = l31, vr1 = 32 + l31;
          bf16x8 va0 = *(const bf16x8*)&Vs[vr0 * 128 + (kslot ^ (vr0 & 15)) * 8];
          bf16x8 va1 = *(const bf16x8*)&Vs[vr1 * 128 + (kslot ^ (vr1 & 15)) * 8];
          oA = __builtin_amdgcn_mfma_f32_32x32x16_bf16(va0, pb, oA, 0, 0, 0);
          oB = __builtin_amdgcn_mfma_f32_32x32x16_bf16(va1, pb, oB, 0, 0, 0);
        }
      }
    }
  }

  float l_tot = l_run + __shfl_xor(l_run, 32, 64);
  float inv = 1.f / l_tot;
  int mrow = qrow * 2 + b;
  u16* op = Out + (size_t)mrow * DM + h * 64;
  #pragma unroll
  for (int db = 0; db < 2; ++db) {
    f32x16 o = db ? oB : oA;
    #pragma unroll
    for (int g = 0; g < 4; ++g) {
      int d0 = db * 32 + 8 * g + 4 * l5;
      ushort4 st;
      st.x = f2bf(o[4 * g + 0] * inv);
      st.y = f2bf(o[4 * g + 1] * inv);
      st.z = f2bf(o[4 * g + 2] * inv);
      st.w = f2bf(o[4 * g + 3] * inv);
      *(ushort4*)(op + d0) = st;
    }
  }
}

// ---------- fused LayerNorm: x = addf + bvec + sum of 4 bf16 partials; LN -> Yf (+Yb) ----------
__device__ __forceinline__ float wave_sum(float v) {
  #pragma unroll
  for (int off = 32; off >= 1; off >>= 1) v += __shfl_xor(v, off, 64);
  return v;
}

template <int WB>
__global__ __launch_bounds__(256) void k_lnp(const u16* __restrict__ pb, const float* __restrict__ addf,
                                             const float* __restrict__ bvec,
                                             const float* __restrict__ gw, const float* __restrict__ bw,
                                             float* __restrict__ Yf, u16* __restrict__ Yb) {
  int m = blockIdx.x;
  int tid = threadIdx.x, lane = tid & 63, w = tid >> 6;
  __shared__ float part[4];
  __shared__ float shv[2];
  float4 sc = ((const float4*)(addf + (size_t)m * DM))[tid];
  float4 bv = ((const float4*)bvec)[tid];
  float vx = sc.x + bv.x, vy = sc.y + bv.y, vz = sc.z + bv.z, vw = sc.w + bv.w;
  #pragma unroll
  for (int z = 0; z < 4; ++z) {
    ushort4 qv = ((const ushort4*)(pb + (size_t)z * MROWS * DM + (size_t)m * DM))[tid];
    vx += bf2f(qv.x); vy += bf2f(qv.y); vz += bf2f(qv.z); vw += bf2f(qv.w);
  }
  float s = wave_sum(vx + vy + vz + vw);
  if (lane == 0) part[w] = s;
  __syncthreads();
  if (tid == 0) shv[0] = (part[0] + part[1] + part[2] + part[3]) * (1.f / DM);
  __syncthreads();
  float mu = shv[0];
  float d0 = vx - mu, d1 = vy - mu, d2 = vz - mu, d3 = vw - mu;
  float q = wave_sum(d0 * d0 + d1 * d1 + d2 * d2 + d3 * d3);
  if (lane == 0) part[w] = q;
  __syncthreads();
  if (tid == 0) shv[1] = rsqrtf((part[0] + part[1] + part[2] + part[3]) * (1.f / DM) + 1e-5f);
  __syncthreads();
  float rstd = shv[1];
  float4 g4 = ((const float4*)gw)[tid];
  float4 b4 = ((const float4*)bw)[tid];
  float y0 = d0 * rstd * g4.x + b4.x;
  float y1 = d1 * rstd * g4.y + b4.y;
  float y2 = d2 * rstd * g4.z + b4.z;
  float y3 = d3 * rstd * g4.w + b4.w;
  ((float4*)(Yf + (size_t)m * DM))[tid] = make_float4(y0, y1, y2, y3);
  if (WB) {
    ushort4 o;
    o.x = f2bf(y0); o.y = f2bf(y1); o.z = f2bf(y2); o.w = f2bf(y3);
    ((ushort4*)(Yb + (size_t)m * DM))[tid] = o;
  }
}

extern "C" void kernel_launch(void* const* d_in, const int* in_sizes, int n_in,
                              void* d_out, int out_size, void* d_ws, size_t ws_size,
                              hipStream_t stream) {
  (void)in_sizes; (void)n_in; (void)out_size; (void)ws_size;
  const float* src  = (const float*)d_in[0];
  const float* mask = (const float*)d_in[1];
  const float* Wq = (const float*)d_in[2];  const float* bq  = (const float*)d_in[3];
  const float* Wk = (const float*)d_in[4];  const float* bk  = (const float*)d_in[5];
  const float* Wv = (const float*)d_in[6];  const float* bv  = (const float*)d_in[7];
  const float* Wo = (const float*)d_in[8];  const float* bo  = (const float*)d_in[9];
  const float* W1 = (const float*)d_in[10]; const float* b1  = (const float*)d_in[11];
  const float* W2 = (const float*)d_in[12]; const float* b2  = (const float*)d_in[13];
  const float* g1 = (const float*)d_in[14]; const float* be1 = (const float*)d_in[15];
  const float* g2 = (const float*)d_in[16]; const float* be2 = (const float*)d_in[17];
  float* out = (float*)d_out;

  char* base = (char*)d_ws;
  size_t off = 0;
  auto carve = [&](size_t bytes) -> void* {
    void* r = base + off;
    off += (bytes + 255) & ~(size_t)255;
    return r;
  };
  u16* Wq_t = (u16*)carve(2ull * 1024 * 1024);  // Wq_t/Wk_t/Wv_t contiguous -> fused N=3072 GEMM
  u16* Wk_t = (u16*)carve(2ull * 1024 * 1024);
  u16* Wv_t = (u16*)carve(2ull * 1024 * 1024);
  u16* Wo_t = (u16*)carve(2ull * 1024 * 1024);
  u16* W1_t = (u16*)carve(2ull * 4096 * 1024);
  u16* W2_t = (u16*)carve(2ull * 1024 * 4096);
  u16* Xbf  = (u16*)carve(2ull * 4096 * 1024);
  float* cosT = (float*)carve(4ull * 2048 * 32);
  float* sinT = (float*)carve(4ull * 2048 * 32);
  float* bqkv = (float*)carve(4ull * 3072);
  unsigned char* mflags = (unsigned char*)carve(1024);
  u16* attn_out = (u16*)carve(2ull * 4096 * 1024);
  float* src2f = (float*)carve(4ull * 4096 * 1024);     // dedicated: live LN1 -> LN2
  float* QKV = (float*)carve(4ull * 4096 * 3072);       // 48MB, multiply reused (see below)
  u16* Qh = (u16*)carve(2ull * 32 * 2048 * 64);         // 8MB
  u16* Kh = (u16*)carve(2ull * 32 * 2048 * 64);         // 8MB (contiguous after Qh)
  u16* Vt = (u16*)carve(2ull * 32 * 2048 * 64);         // 8MB
  // Aliases (lifetimes):
  //   QKV fp32 (48MB): dead after rope_heads.
  //     woPb = QKV+0 (4 x 8MB bf16)                : Wo split-K=4 partials, consumed by LN1.
  //     ff1  = QKV+0 (32MB bf16)                   : written by FF1 after LN1 (woPb dead).
  //     ffPb = QKV+32MB .. +64MB (4 x 8MB bf16)    : FF2 partials; spans QKV tail + Qh + Kh
  //                                                  (Qh/Kh dead after attn). Consumed by LN2.
  //   src2b = Vt (8MB bf16): Vt dead after attn; consumed by FF1.
  u16* woPb = (u16*)QKV;
  u16* ff1 = (u16*)QKV;
  u16* ffPb = (u16*)((char*)QKV + 32ull * 1024 * 1024);
  u16* src2b = (u16*)Vt;

  dim3 blk(256);
  dim3 blk5(512);
  k_transpose_bf16<<<dim3(32, 32), blk, 0, stream>>>(Wq, Wq_t, 1024, 1024);
  k_transpose_bf16<<<dim3(32, 32), blk, 0, stream>>>(Wk, Wk_t, 1024, 1024);
  k_transpose_bf16<<<dim3(32, 32), blk, 0, stream>>>(Wv, Wv_t, 1024, 1024);
  k_transpose_bf16<<<dim3(32, 32), blk, 0, stream>>>(Wo, Wo_t, 1024, 1024);
  k_transpose_bf16<<<dim3(128, 32), blk, 0, stream>>>(W1, W1_t, 1024, 4096);
  k_transpose_bf16<<<dim3(32, 128), blk, 0, stream>>>(W2, W2_t, 4096, 1024);
  k_f2bf4<<<dim3(4096), blk, 0, stream>>>((const float4*)src, (ushort4*)Xbf, 4096 * 1024 / 4);
  k_rope_table<<<dim3(256), blk, 0, stream>>>(cosT, sinT);
  k_cat3<<<dim3(12), blk, 0, stream>>>(bq, bk, bv, bqkv);
  k_mask_flags<<<dim3(32, 32), blk, 0, stream>>>(mask, mflags);
  // fused QKV projection (M=4096, N=3072, K=1024): 12x16 = 192 blocks
  k_gemm256<EPI_F32><<<dim3(12, 16, 1), blk5, 0, stream>>>(Xbf, Wq_t, bqkv, QKV, nullptr, 4096, 3072, 1024, 3072, 1024);
  k_rope_heads<<<dim3(MROWS * 512 / 256), blk, 0, stream>>>(QKV, cosT, sinT, Qh, Kh, Vt);
  k_attn<<<dim3(16, 32), blk, 0, stream>>>(Qh, Kh, Vt, mask, mflags, attn_out);
  // O-projection: split-K=4 (4x16x4 = 256 blocks), bf16 partials -> LN1
  k_gemm256<EPI_PARTB><<<dim3(4, 16, 4), blk5, 0, stream>>>(attn_out, Wo_t, nullptr, nullptr, woPb, 4096, 1024, 1024, 1024, 256);
  k_lnp<1><<<dim3(4096), blk, 0, stream>>>(woPb, src, bo, g1, be1, src2f, src2b);
  // FF1 with ReLU (16x16 = 256 blocks)
  k_gemm256<EPI_RELU_BF16><<<dim3(16, 16, 1), blk5, 0, stream>>>(src2b, W1_t, b1, nullptr, ff1, 4096, 4096, 1024, 4096, 1024);
  // FF2: split-K=4 (4x16x4 = 256 blocks), bf16 partials -> LN2
  k_gemm256<EPI_PARTB><<<dim3(4, 16, 4), blk5, 0, stream>>>(ff1, W2_t, nullptr, nullptr, ffPb, 4096, 1024, 4096, 1024, 1024);
  k_lnp<0><<<dim3(4096), blk, 0, stream>>>(ffPb, src2f, b2, g2, be2, out, nullptr);
}

// Round 7
// 302.315 us; speedup vs baseline: 1.5842x; 1.0465x over previous
//
#include <hip/hip_runtime.h>
#include <math.h>

#define S_LEN 2048
#define DM 1024
#define NH 16
#define HD 64
#define DFF 4096
#define MROWS 4096  // S_LEN * 2 batch

typedef unsigned short u16;
typedef __attribute__((ext_vector_type(8))) __bf16 bf16x8;
typedef __attribute__((ext_vector_type(4))) float f32x4;
typedef __attribute__((ext_vector_type(16))) float f32x16;
typedef __attribute__((ext_vector_type(4))) int int32x4;

__device__ __forceinline__ u16 f2bf(float f) {
  unsigned u = __float_as_uint(f);
  unsigned r = (u + 0x7fffu + ((u >> 16) & 1u)) >> 16;  // RNE
  return (u16)r;
}

__device__ __forceinline__ float bf2f(u16 u) {
  return __uint_as_float((unsigned)u << 16);
}

__device__ __forceinline__ unsigned cvtpk_bf16(float lo, float hi) {
  unsigned r;
  asm("v_cvt_pk_bf16_f32 %0, %1, %2" : "=v"(r) : "v"(lo), "v"(hi));
  return r;
}

__device__ __forceinline__ void gload_lds16(const void* g, void* l) {
  __builtin_amdgcn_global_load_lds((__attribute__((address_space(1))) void*)g,
                                   (__attribute__((address_space(3))) void*)l, 16, 0, 0);
}

// ---------- 4x fused transpose + fp32->bf16 weights (1024x1024): W -> Wt ----------
__global__ __launch_bounds__(256) void k_transpose4(const float* __restrict__ W0, const float* __restrict__ W1,
                                                    const float* __restrict__ W2, const float* __restrict__ W3,
                                                    u16* __restrict__ T0, u16* __restrict__ T1,
                                                    u16* __restrict__ T2, u16* __restrict__ T3) {
  __shared__ float tile[32][33];
  const float* W = blockIdx.z == 0 ? W0 : blockIdx.z == 1 ? W1 : blockIdx.z == 2 ? W2 : W3;
  u16* Wt = blockIdx.z == 0 ? T0 : blockIdx.z == 1 ? T1 : blockIdx.z == 2 ? T2 : T3;
  int n0 = blockIdx.x * 32, k0 = blockIdx.y * 32;
  int tx = threadIdx.x & 31, ty = threadIdx.x >> 5;
  #pragma unroll
  for (int r = ty; r < 32; r += 8) tile[r][tx] = W[(size_t)(k0 + r) * 1024 + n0 + tx];
  __syncthreads();
  #pragma unroll
  for (int r = ty; r < 32; r += 8) Wt[(size_t)(n0 + r) * 1024 + k0 + tx] = f2bf(tile[tx][r]);
}

__global__ __launch_bounds__(256) void k_transpose_bf16(const float* __restrict__ W,
                                                        u16* __restrict__ Wt, int K, int N) {
  __shared__ float tile[32][33];
  int n0 = blockIdx.x * 32, k0 = blockIdx.y * 32;
  int tx = threadIdx.x & 31, ty = threadIdx.x >> 5;
  #pragma unroll
  for (int r = ty; r < 32; r += 8) tile[r][tx] = W[(size_t)(k0 + r) * N + n0 + tx];
  __syncthreads();
  #pragma unroll
  for (int r = ty; r < 32; r += 8) Wt[(size_t)(n0 + r) * K + k0 + tx] = f2bf(tile[tx][r]);
}

__global__ __launch_bounds__(256) void k_f2bf4(const float4* __restrict__ in,
                                               ushort4* __restrict__ out, int n4) {
  int i = blockIdx.x * 256 + threadIdx.x;
  if (i >= n4) return;
  float4 v = in[i];
  ushort4 o;
  o.x = f2bf(v.x); o.y = f2bf(v.y); o.z = f2bf(v.z); o.w = f2bf(v.w);
  out[i] = o;
}

__global__ __launch_bounds__(256) void k_rope_table(float* __restrict__ cosT,
                                                    float* __restrict__ sinT) {
  int idx = blockIdx.x * 256 + threadIdx.x;
  if (idx >= S_LEN * 32) return;
  int s = idx >> 5, i = idx & 31;
  float inv = powf(10000.f, -(float)(2 * i) / 64.f);
  float ang = (float)s * inv;
  cosT[idx] = cosf(ang);
  sinT[idx] = sinf(ang);
}

__global__ __launch_bounds__(256) void k_cat3(const float* __restrict__ a, const float* __restrict__ b,
                                              const float* __restrict__ c, float* __restrict__ o) {
  int i = blockIdx.x * 256 + threadIdx.x;
  if (i >= 3072) return;
  o[i] = i < 1024 ? a[i] : (i < 2048 ? b[i - 1024] : c[i - 2048]);
}

// ---------- mask tile flags: 0 = all pass (>=0.1), 1 = mixed/masked ----------
__global__ __launch_bounds__(256) void k_mask_flags(const float* __restrict__ mask,
                                                    unsigned char* __restrict__ flags) {
  int kt = blockIdx.x, qt = blockIdx.y;
  const float* mp = mask + (size_t)(qt * 64) * S_LEN + kt * 64;
  int tr = threadIdx.x >> 2;
  int tc = (threadIdx.x & 3) * 16;
  int ok = 1;
  #pragma unroll
  for (int c = 0; c < 16; c += 4) {
    float4 v = *(const float4*)(mp + (size_t)tr * S_LEN + tc + c);
    ok &= (v.x >= 0.1f) & (v.y >= 0.1f) & (v.z >= 0.1f) & (v.w >= 0.1f);
  }
  ok = __all(ok) ? 1 : 0;
  __shared__ int sh[4];
  if ((threadIdx.x & 63) == 0) sh[threadIdx.x >> 6] = ok;
  __syncthreads();
  if (threadIdx.x == 0) flags[qt * 32 + kt] = (sh[0] & sh[1] & sh[2] & sh[3]) ? 0 : 1;
}

// ---------- 256x256-tile pipelined bf16 GEMM ----------
enum { EPI_F32 = 0, EPI_RELU_BF16 = 2, EPI_PARTB = 4, EPI_BF16 = 5 };

template <int EPI>
__global__ __launch_bounds__(512, 2) void k_gemm256(const u16* __restrict__ A,
                                                    const u16* __restrict__ Bt,
                                                    const float* __restrict__ bias,
                                                    float* __restrict__ Cf, u16* __restrict__ Cb,
                                                    int M, int N, int K, int ldc, int Kc) {
  __shared__ __attribute__((aligned(16))) u16 As[4][256 * 32];
  __shared__ __attribute__((aligned(16))) u16 Bs[4][256 * 32];

  int nx = gridDim.x;
  int nwg = nx * gridDim.y;
  int flat = blockIdx.y * nx + blockIdx.x;
  int id = (flat & 7) * (nwg >> 3) + (flat >> 3);
  int n0 = (id % nx) * 256;
  int m0 = (id / nx) * 256;
  int kz = blockIdx.z * Kc;

  int tid = threadIdx.x;
  int lane = tid & 63, w = tid >> 6;
  int wm = (w >> 2) * 128, wn = (w & 3) * 64;
  int l15 = lane & 15, l4 = lane >> 4;
  int NT = Kc >> 5;

  const u16* aS[2];
  const u16* bS[2];
  int dslot[2];
  #pragma unroll
  for (int j = 0; j < 2; ++j) {
    int P = j * 512 + tid;
    int r = P >> 2;
    int sl = (P & 3) ^ (r & 3);
    aS[j] = A + (size_t)(m0 + r) * K + kz + sl * 8;
    bS[j] = Bt + (size_t)(n0 + r) * K + kz + sl * 8;
    dslot[j] = j * 512 + w * 64;
  }

  f32x4 acc[8][4] = {};

  #pragma unroll
  for (int t = 0; t < 3; ++t) {
    #pragma unroll
    for (int j = 0; j < 2; ++j) {
      gload_lds16(aS[j] + t * 32, &As[t][dslot[j] * 8]);
      gload_lds16(bS[j] + t * 32, &Bs[t][dslot[j] * 8]);
    }
  }

  for (int t = 0; t < NT; ++t) {
    int buf = t & 3;
    if (t < NT - 2) asm volatile("s_waitcnt vmcnt(8)" ::: "memory");
    else if (t == NT - 2) asm volatile("s_waitcnt vmcnt(4)" ::: "memory");
    else asm volatile("s_waitcnt vmcnt(0)" ::: "memory");
    __builtin_amdgcn_s_barrier();

    if (t + 3 < NT) {
      int tn = t + 3;
      int bn = tn & 3;
      #pragma unroll
      for (int j = 0; j < 2; ++j) {
        gload_lds16(aS[j] + tn * 32, &As[bn][dslot[j] * 8]);
        gload_lds16(bS[j] + tn * 32, &Bs[bn][dslot[j] * 8]);
      }
    }

    bf16x8 af[8], bq[4];
    #pragma unroll
    for (int m = 0; m < 8; ++m) {
      int r = wm + m * 16 + l15;
      af[m] = *(const bf16x8*)&As[buf][r * 32 + (l4 ^ (r & 3)) * 8];
    }
    #pragma unroll
    for (int n = 0; n < 4; ++n) {
      int r = wn + n * 16 + l15;
      bq[n] = *(const bf16x8*)&Bs[buf][r * 32 + (l4 ^ (r & 3)) * 8];
    }
    __builtin_amdgcn_s_setprio(1);
    #pragma unroll
    for (int m = 0; m < 8; ++m)
      #pragma unroll
      for (int n = 0; n < 4; ++n)
        acc[m][n] = __builtin_amdgcn_mfma_f32_16x16x32_bf16(af[m], bq[n], acc[m][n], 0, 0, 0);
    __builtin_amdgcn_s_setprio(0);
  }

  size_t zoff = (size_t)blockIdx.z * M * ldc;
  #pragma unroll
  for (int m = 0; m < 8; ++m) {
    #pragma unroll
    for (int n = 0; n < 4; ++n) {
      int col = n0 + wn + n * 16 + l15;
      float bv = (EPI == EPI_PARTB) ? 0.f : bias[col];
      #pragma unroll
      for (int r = 0; r < 4; ++r) {
        int row = m0 + wm + m * 16 + l4 * 4 + r;
        float v = acc[m][n][r] + bv;
        size_t o = (size_t)row * ldc + col;
        if (EPI == EPI_F32) Cf[o] = v;
        else if (EPI == EPI_RELU_BF16) Cb[o] = f2bf(fmaxf(v, 0.f));
        else if (EPI == EPI_BF16) Cb[o] = f2bf(v);
        else Cb[zoff + o] = f2bf(v);
      }
    }
  }
}

// ---------- RoPE + head-split (bf16 QKV in); Q pre-scaled by log2(e)/sqrt(HD) ----------
#define QSCALE 0.180336881f
__global__ __launch_bounds__(256) void k_rope_heads(const u16* __restrict__ QKVb,
                                                    const float* __restrict__ cosT,
                                                    const float* __restrict__ sinT,
                                                    u16* __restrict__ Qh, u16* __restrict__ Kh,
                                                    u16* __restrict__ Vt) {
  int idx = blockIdx.x * 256 + threadIdx.x;
  if (idx >= MROWS * 512) return;
  int m = idx >> 9, c2 = idx & 511;
  int h = c2 >> 5, i = c2 & 31, d = 2 * i;
  int s = m >> 1, b = m & 1;
  int bh = b * NH + h;
  size_t base = (size_t)m * 3072 + h * 64 + d;
  float q0 = bf2f(QKVb[base]), q1 = bf2f(QKVb[base + 1]);
  float k0 = bf2f(QKVb[base + 1024]), k1 = bf2f(QKVb[base + 1025]);
  float v0 = bf2f(QKVb[base + 2048]), v1 = bf2f(QKVb[base + 2049]);
  float c = cosT[s * 32 + i], sn = sinT[s * 32 + i];
  size_t ho = ((size_t)bh * S_LEN + s) * 64 + d;
  Qh[ho]     = f2bf((q0 * c - q1 * sn) * QSCALE);
  Qh[ho + 1] = f2bf((q1 * c + q0 * sn) * QSCALE);
  Kh[ho]     = f2bf(k0 * c - k1 * sn);
  Kh[ho + 1] = f2bf(k1 * c + k0 * sn);
  size_t vo = ((size_t)bh * 64 + d) * S_LEN + s;
  Vt[vo] = f2bf(v0);
  Vt[vo + S_LEN] = f2bf(v1);
}

// ---------- flash attention: swapped-QK^T 32x32x16, in-register softmax,
//            double-buffered LDS 2-phase pipeline, XCD-grouped heads ----------
__global__ __launch_bounds__(256) void k_attn(const u16* __restrict__ Qh, const u16* __restrict__ Kh,
                                              const u16* __restrict__ Vt,
                                              const float* __restrict__ mask,
                                              const unsigned char* __restrict__ flags,
                                              u16* __restrict__ Out) {
  __shared__ __attribute__((aligned(16))) u16 Ks[2][128 * 64];
  __shared__ __attribute__((aligned(16))) u16 Vs[2][64 * 128];
  // XCD swizzle: flat id f -> xcd = f&7 owns heads [xcd*4, xcd*4+4)  (512 KB K/V per head)
  int f = blockIdx.y * gridDim.x + blockIdx.x;  // gridDim = (16, 32)
  int xcd = f & 7, ii = f >> 3;
  int bh = xcd * 4 + (ii >> 4);
  int q0 = (ii & 15) * 128;
  int b = bh >> 4, h = bh & 15;
  int tid = threadIdx.x, lane = tid & 63, w = tid >> 6;
  int l31 = lane & 31, l5 = lane >> 5;

  int qrow = q0 + w * 32 + l31;
  int qt = qrow >> 6;  // wave-uniform

  bf16x8 qf[4];
  {
    const u16* qp = Qh + ((size_t)bh * S_LEN + qrow) * 64 + l5 * 8;
    #pragma unroll
    for (int dc = 0; dc < 4; ++dc) qf[dc] = *(const bf16x8*)(qp + dc * 16);
  }

  const u16* Kbase = Kh + (size_t)bh * S_LEN * 64;
  const u16* Vbase = Vt + (size_t)bh * 64 * S_LEN;

  // per-thread staging addresses (4 K slots + 4 V slots of 16B each)
  int ksid[4], vsid[4];
  const u16* kg[4];
  const u16* vg[4];
  #pragma unroll
  for (int i = 0; i < 4; ++i) {
    int sid = i * 256 + tid;
    ksid[i] = sid;
    int kr = sid >> 3, kslot = sid & 7;
    kg[i] = Kbase + (size_t)kr * 64 + (kslot ^ (kr & 7)) * 8;  // + kv0*64 per tile
    vsid[i] = sid;
    int vr = sid >> 4, vslot = sid & 15;
    vg[i] = Vbase + (size_t)vr * S_LEN + ((vslot ^ (vr & 15))) * 8;  // + kv0 per tile
  }

  float m_run = -1e30f, l_run = 0.f;
  f32x16 oA = {}, oB = {};

  const int NTILE = S_LEN / 128;
  // prologue: stage tile 0 into buf 0
  #pragma unroll
  for (int i = 0; i < 4; ++i) {
    gload_lds16(kg[i], &Ks[0][ksid[i] * 8]);
    gload_lds16(vg[i], &Vs[0][vsid[i] * 8]);
  }

  for (int t = 0; t < NTILE; ++t) {
    int cur = t & 1;
    int kv0 = t * 128;
    asm volatile("s_waitcnt vmcnt(0)" ::: "memory");  // tile t landed
    __builtin_amdgcn_s_barrier();                     // all waves past compute(t-1)
    if (t + 1 < NTILE) {                              // stage t+1 under compute(t)
      int kvn = (t + 1) * 128;
      #pragma unroll
      for (int i = 0; i < 4; ++i) {
        gload_lds16(kg[i] + (size_t)kvn * 64, &Ks[cur ^ 1][ksid[i] * 8]);
        gload_lds16(vg[i] + kvn, &Vs[cur ^ 1][vsid[i] * 8]);
      }
    }

    #pragma unroll
    for (int ksub = 0; ksub < 2; ++ksub) {
      int koff = ksub * 64;
      f32x16 sA = {}, sB = {};
      #pragma unroll
      for (int dc = 0; dc < 4; ++dc) {
        int r0 = koff + l31;
        int r1 = koff + 32 + l31;
        int slot = (dc * 2 + l5) ^ (l31 & 7);
        bf16x8 ka0 = *(const bf16x8*)&Ks[cur][r0 * 64 + slot * 8];
        bf16x8 ka1 = *(const bf16x8*)&Ks[cur][r1 * 64 + slot * 8];
        sA = __builtin_amdgcn_mfma_f32_32x32x16_bf16(ka0, qf[dc], sA, 0, 0, 0);
        sB = __builtin_amdgcn_mfma_f32_32x32x16_bf16(ka1, qf[dc], sB, 0, 0, 0);
      }

      int fl = flags[qt * 32 + ((kv0 + koff) >> 6)];
      if (fl) {
        const float* mrow = mask + (size_t)qrow * S_LEN + kv0 + koff;
        #pragma unroll
        for (int r = 0; r < 16; ++r) {
          int key = (r & 3) + 8 * (r >> 2) + 4 * l5;
          if (mrow[key] < 0.1f) sA[r] = -1e30f;
          if (mrow[key + 32] < 0.1f) sB[r] = -1e30f;
        }
      }

      float pm = m_run;
      #pragma unroll
      for (int r = 0; r < 16; ++r) pm = fmaxf(pm, fmaxf(sA[r], sB[r]));
      pm = fmaxf(pm, __shfl_xor(pm, 32, 64));
      if (!__all(pm <= m_run + 8.f)) {  // defer-max (log2 units)
        float corr = __builtin_amdgcn_exp2f(m_run - pm);
        m_run = pm;
        l_run *= corr;
        #pragma unroll
        for (int r = 0; r < 16; ++r) { oA[r] *= corr; oB[r] *= corr; }
      }
      float ps = 0.f;
      #pragma unroll
      for (int r = 0; r < 16; ++r) {
        sA[r] = __builtin_amdgcn_exp2f(sA[r] - m_run);
        sB[r] = __builtin_amdgcn_exp2f(sB[r] - m_run);
        ps += sA[r] + sB[r];
      }
      l_run += ps;

      #pragma unroll
      for (int kh = 0; kh < 2; ++kh) {
        f32x16 s = kh ? sB : sA;
        #pragma unroll
        for (int c = 0; c < 2; ++c) {
          int base = c * 8;
          unsigned u0 = cvtpk_bf16(s[base + 0], s[base + 1]);
          unsigned u1 = cvtpk_bf16(s[base + 2], s[base + 3]);
          unsigned u2 = cvtpk_bf16(s[base + 4], s[base + 5]);
          unsigned u3 = cvtpk_bf16(s[base + 6], s[base + 7]);
          asm volatile("v_permlane32_swap_b32 %0, %1" : "+v"(u0), "+v"(u2));
          asm volatile("v_permlane32_swap_b32 %0, %1" : "+v"(u1), "+v"(u3));
          int32x4 wds = {(int)u0, (int)u1, (int)u2, (int)u3};
          bf16x8 pb = *(bf16x8*)&wds;
          int kslot = ksub * 8 + (kh * 2 + c) * 2 + l5;
          int vr0 = l31, vr1 = 32 + l31;
          bf16x8 va0 = *(const bf16x8*)&Vs[cur][vr0 * 128 + (kslot ^ (vr0 & 15)) * 8];
          bf16x8 va1 = *(const bf16x8*)&Vs[cur][vr1 * 128 + (kslot ^ (vr1 & 15)) * 8];
          oA = __builtin_amdgcn_mfma_f32_32x32x16_bf16(va0, pb, oA, 0, 0, 0);
          oB = __builtin_amdgcn_mfma_f32_32x32x16_bf16(va1, pb, oB, 0, 0, 0);
        }
      }
    }
  }

  float l_tot = l_run + __shfl_xor(l_run, 32, 64);
  float inv = 1.f / l_tot;
  int mrow = qrow * 2 + b;
  u16* op = Out + (size_t)mrow * DM + h * 64;
  #pragma unroll
  for (int db = 0; db < 2; ++db) {
    f32x16 o = db ? oB : oA;
    #pragma unroll
    for (int g = 0; g < 4; ++g) {
      int d0 = db * 32 + 8 * g + 4 * l5;
      ushort4 st;
      st.x = f2bf(o[4 * g + 0] * inv);
      st.y = f2bf(o[4 * g + 1] * inv);
      st.z = f2bf(o[4 * g + 2] * inv);
      st.w = f2bf(o[4 * g + 3] * inv);
      *(ushort4*)(op + d0) = st;
    }
  }
}

// ---------- fused LayerNorm: x = addf + bvec + sum of 4 bf16 partials; LN -> Yf (+Yb) ----------
__device__ __forceinline__ float wave_sum(float v) {
  #pragma unroll
  for (int off = 32; off >= 1; off >>= 1) v += __shfl_xor(v, off, 64);
  return v;
}

template <int WB>
__global__ __launch_bounds__(256) void k_lnp(const u16* __restrict__ pb, const float* __restrict__ addf,
                                             const float* __restrict__ bvec,
                                             const float* __restrict__ gw, const float* __restrict__ bw,
                                             float* __restrict__ Yf, u16* __restrict__ Yb) {
  int m = blockIdx.x;
  int tid = threadIdx.x, lane = tid & 63, w = tid >> 6;
  __shared__ float part[4];
  __shared__ float shv[2];
  float4 sc = ((const float4*)(addf + (size_t)m * DM))[tid];
  float4 bv = ((const float4*)bvec)[tid];
  float vx = sc.x + bv.x, vy = sc.y + bv.y, vz = sc.z + bv.z, vw = sc.w + bv.w;
  #pragma unroll
  for (int z = 0; z < 4; ++z) {
    ushort4 qv = ((const ushort4*)(pb + (size_t)z * MROWS * DM + (size_t)m * DM))[tid];
    vx += bf2f(qv.x); vy += bf2f(qv.y); vz += bf2f(qv.z); vw += bf2f(qv.w);
  }
  float s = wave_sum(vx + vy + vz + vw);
  if (lane == 0) part[w] = s;
  __syncthreads();
  if (tid == 0) shv[0] = (part[0] + part[1] + part[2] + part[3]) * (1.f / DM);
  __syncthreads();
  float mu = shv[0];
  float d0 = vx - mu, d1 = vy - mu, d2 = vz - mu, d3 = vw - mu;
  float q = wave_sum(d0 * d0 + d1 * d1 + d2 * d2 + d3 * d3);
  if (lane == 0) part[w] = q;
  __syncthreads();
  if (tid == 0) shv[1] = rsqrtf((part[0] + part[1] + part[2] + part[3]) * (1.f / DM) + 1e-5f);
  __syncthreads();
  float rstd = shv[1];
  float4 g4 = ((const float4*)gw)[tid];
  float4 b4 = ((const float4*)bw)[tid];
  float y0 = d0 * rstd * g4.x + b4.x;
  float y1 = d1 * rstd * g4.y + b4.y;
  float y2 = d2 * rstd * g4.z + b4.z;
  float y3 = d3 * rstd * g4.w + b4.w;
  ((float4*)(Yf + (size_t)m * DM))[tid] = make_float4(y0, y1, y2, y3);
  if (WB) {
    ushort4 o;
    o.x = f2bf(y0); o.y = f2bf(y1); o.z = f2bf(y2); o.w = f2bf(y3);
    ((ushort4*)(Yb + (size_t)m * DM))[tid] = o;
  }
}

extern "C" void kernel_launch(void* const* d_in, const int* in_sizes, int n_in,
                              void* d_out, int out_size, void* d_ws, size_t ws_size,
                              hipStream_t stream) {
  (void)in_sizes; (void)n_in; (void)out_size; (void)ws_size;
  const float* src  = (const float*)d_in[0];
  const float* mask = (const float*)d_in[1];
  const float* Wq = (const float*)d_in[2];  const float* bq  = (const float*)d_in[3];
  const float* Wk = (const float*)d_in[4];  const float* bk  = (const float*)d_in[5];
  const float* Wv = (const float*)d_in[6];  const float* bv  = (const float*)d_in[7];
  const float* Wo = (const float*)d_in[8];  const float* bo  = (const float*)d_in[9];
  const float* W1 = (const float*)d_in[10]; const float* b1  = (const float*)d_in[11];
  const float* W2 = (const float*)d_in[12]; const float* b2  = (const float*)d_in[13];
  const float* g1 = (const float*)d_in[14]; const float* be1 = (const float*)d_in[15];
  const float* g2 = (const float*)d_in[16]; const float* be2 = (const float*)d_in[17];
  float* out = (float*)d_out;

  char* base = (char*)d_ws;
  size_t off = 0;
  auto carve = [&](size_t bytes) -> void* {
    void* r = base + off;
    off += (bytes + 255) & ~(size_t)255;
    return r;
  };
  u16* Wq_t = (u16*)carve(2ull * 1024 * 1024);  // Wq_t/Wk_t/Wv_t contiguous -> fused N=3072 GEMM
  u16* Wk_t = (u16*)carve(2ull * 1024 * 1024);
  u16* Wv_t = (u16*)carve(2ull * 1024 * 1024);
  u16* Wo_t = (u16*)carve(2ull * 1024 * 1024);
  u16* W1_t = (u16*)carve(2ull * 4096 * 1024);
  u16* W2_t = (u16*)carve(2ull * 1024 * 4096);
  u16* Xbf  = (u16*)carve(2ull * 4096 * 1024);
  float* cosT = (float*)carve(4ull * 2048 * 32);
  float* sinT = (float*)carve(4ull * 2048 * 32);
  float* bqkv = (float*)carve(4ull * 3072);
  unsigned char* mflags = (unsigned char*)carve(1024);
  u16* attn_out = (u16*)carve(2ull * 4096 * 1024);
  float* src2f = (float*)carve(4ull * 4096 * 1024);     // dedicated: live LN1 -> LN2
  float* QKV = (float*)carve(4ull * 4096 * 3072);       // 48MB region, multiply reused
  u16* Qh = (u16*)carve(2ull * 32 * 2048 * 64);         // 8MB
  u16* Kh = (u16*)carve(2ull * 32 * 2048 * 64);         // 8MB
  u16* Vt = (u16*)carve(2ull * 32 * 2048 * 64);         // 8MB
  // Aliases (lifetimes):
  //   QKVb = QKV region as bf16 (24MB): dead after rope_heads.
  //   woPb = QKV+0 (4 x 8MB bf16): Wo split-K=4 partials, consumed by LN1.
  //   ff1  = QKV+0 (32MB bf16): written by FF1 after LN1 (woPb dead).
  //   ffPb = QKV+32MB..+64MB (4 x 8MB bf16): FF2 partials; spans QKV tail + Qh + Kh
  //          (Qh/Kh dead after attn). Consumed by LN2.
  //   src2b = Vt (8MB bf16): Vt dead after attn; consumed by FF1.
  u16* QKVb = (u16*)QKV;
  u16* woPb = (u16*)QKV;
  u16* ff1 = (u16*)QKV;
  u16* ffPb = (u16*)((char*)QKV + 32ull * 1024 * 1024);
  u16* src2b = (u16*)Vt;

  dim3 blk(256);
  dim3 blk5(512);
  k_transpose4<<<dim3(32, 32, 4), blk, 0, stream>>>(Wq, Wk, Wv, Wo, Wq_t, Wk_t, Wv_t, Wo_t);
  k_transpose_bf16<<<dim3(128, 32), blk, 0, stream>>>(W1, W1_t, 1024, 4096);
  k_transpose_bf16<<<dim3(32, 128), blk, 0, stream>>>(W2, W2_t, 4096, 1024);
  k_f2bf4<<<dim3(4096), blk, 0, stream>>>((const float4*)src, (ushort4*)Xbf, 4096 * 1024 / 4);
  k_rope_table<<<dim3(256), blk, 0, stream>>>(cosT, sinT);
  k_cat3<<<dim3(12), blk, 0, stream>>>(bq, bk, bv, bqkv);
  k_mask_flags<<<dim3(32, 32), blk, 0, stream>>>(mask, mflags);
  // fused QKV projection (M=4096, N=3072, K=1024) -> bf16
  k_gemm256<EPI_BF16><<<dim3(12, 16, 1), blk5, 0, stream>>>(Xbf, Wq_t, bqkv, nullptr, QKVb, 4096, 3072, 1024, 3072, 1024);
  k_rope_heads<<<dim3(MROWS * 512 / 256), blk, 0, stream>>>(QKVb, cosT, sinT, Qh, Kh, Vt);
  k_attn<<<dim3(16, 32), blk, 0, stream>>>(Qh, Kh, Vt, mask, mflags, attn_out);
  // O-projection: split-K=4, bf16 partials -> LN1
  k_gemm256<EPI_PARTB><<<dim3(4, 16, 4), blk5, 0, stream>>>(attn_out, Wo_t, nullptr, nullptr, woPb, 4096, 1024, 1024, 1024, 256);
  k_lnp<1><<<dim3(4096), blk, 0, stream>>>(woPb, src, bo, g1, be1, src2f, src2b);
  // FF1 with ReLU
  k_gemm256<EPI_RELU_BF16><<<dim3(16, 16, 1), blk5, 0, stream>>>(src2b, W1_t, b1, nullptr, ff1, 4096, 4096, 1024, 4096, 1024);
  // FF2: split-K=4, bf16 partials -> LN2
  k_gemm256<EPI_PARTB><<<dim3(4, 16, 4), blk5, 0, stream>>>(ff1, W2_t, nullptr, nullptr, ffPb, 4096, 1024, 4096, 1024, 1024);
  k_lnp<0><<<dim3(4096), blk, 0, stream>>>(ffPb, src2f, b2, g2, be2, out, nullptr);
}